// Round 1
// baseline (2436.627 us; speedup 1.0000x reference)
//
#include <hip/hip_runtime.h>
#include <math.h>

#define LDP 68   // padded LDS leading dim for 64-wide tiles (68*4B row stride, 16B-aligned)

__device__ __forceinline__ float silu_f(float x) {
    return x * (1.0f / (1.0f + __expf(-x)));
}

// ---------------------------------------------------------------------------
// 1) Down conv as patch GEMM: dcn[r, co], r = b*2048 + img*1024 + p
//    M=4096, K=4096 (ci*16 + kh*4 + kw), N=256
// ---------------------------------------------------------------------------
__global__ __launch_bounds__(256) void k_down(
    const float* __restrict__ x0, const float* __restrict__ x1,
    const float* __restrict__ w, const float* __restrict__ bias,
    float* __restrict__ dcn)
{
    __shared__ float sA[32 * LDP];
    __shared__ float sB[32 * LDP];
    const int tid = threadIdx.x;
    const int mb = blockIdx.x, nb = blockIdx.y;
    const int r0 = mb * 64;
    const int b   = r0 >> 11;
    const int img = (r0 >> 10) & 1;
    const int p0  = r0 & 1023;
    const float* __restrict__ xs = img ? x1 : x0;
    const int H = img ? 256 : 128;
    const int W = img ? 64 : 128;
    const int pwsh   = img ? 4 : 5;
    const int pwmask = img ? 15 : 31;

    const int tm = tid >> 4, tn = tid & 15;
    const int lm = tid >> 3;
    const int lf = tid & 7;
    const int ci_off = lf >> 2, kh = lf & 3;
    const int lco = tid >> 2;
    const int lbf = tid & 3;

    float acc[4][4] = {};

    for (int kt = 0; kt < 4096; kt += 32) {
        const int ci = (kt >> 4) + ci_off;
        #pragma unroll
        for (int rr = 0; rr < 2; ++rr) {
            const int m = lm + rr * 32;
            const int p = p0 + m;
            const int ph = p >> pwsh;
            const int pw = p & pwmask;
            const float4 v = *(const float4*)&xs[(size_t)(((b * 256 + ci) * H + ph * 4 + kh) * W) + pw * 4];
            const int kb = ci_off * 16 + kh * 4;
            sA[(kb + 0) * LDP + m] = v.x;
            sA[(kb + 1) * LDP + m] = v.y;
            sA[(kb + 2) * LDP + m] = v.z;
            sA[(kb + 3) * LDP + m] = v.w;
        }
        {
            const int co = nb * 64 + lco;
            const float4 w1 = *(const float4*)&w[(size_t)co * 4096 + kt + lbf * 4];
            const float4 w2 = *(const float4*)&w[(size_t)co * 4096 + kt + 16 + lbf * 4];
            int kb = lbf * 4;
            sB[(kb + 0) * LDP + lco] = w1.x; sB[(kb + 1) * LDP + lco] = w1.y;
            sB[(kb + 2) * LDP + lco] = w1.z; sB[(kb + 3) * LDP + lco] = w1.w;
            kb = 16 + lbf * 4;
            sB[(kb + 0) * LDP + lco] = w2.x; sB[(kb + 1) * LDP + lco] = w2.y;
            sB[(kb + 2) * LDP + lco] = w2.z; sB[(kb + 3) * LDP + lco] = w2.w;
        }
        __syncthreads();
        #pragma unroll
        for (int k = 0; k < 32; ++k) {
            const float4 av = *(const float4*)&sA[k * LDP + tm * 4];
            const float4 bv = *(const float4*)&sB[k * LDP + tn * 4];
            const float a_[4] = {av.x, av.y, av.z, av.w};
            const float b_[4] = {bv.x, bv.y, bv.z, bv.w};
            #pragma unroll
            for (int i = 0; i < 4; ++i)
                #pragma unroll
                for (int j = 0; j < 4; ++j)
                    acc[i][j] = fmaf(a_[i], b_[j], acc[i][j]);
        }
        __syncthreads();
    }
    #pragma unroll
    for (int i = 0; i < 4; ++i) {
        const int r = r0 + tm * 4 + i;
        #pragma unroll
        for (int j = 0; j < 4; ++j) {
            const int co = nb * 64 + tn * 4 + j;
            dcn[(size_t)r * 256 + co] = acc[i][j] + bias[co];
        }
    }
}

// ---------------------------------------------------------------------------
// 2) LayerNorm over C per position; writes sequence xf[b, s, c] twice
//    (x*_wh ordering is identical to x*_hw in the reference)
// ---------------------------------------------------------------------------
__global__ __launch_bounds__(256) void k_ln(
    const float* __restrict__ dcn, const float* __restrict__ lw,
    const float* __restrict__ lb, float* __restrict__ xf)
{
    const int r = blockIdx.x;      // b*2048 + img*1024 + p
    const int c = threadIdx.x;
    const float v = dcn[(size_t)r * 256 + c];
    float s = v, s2 = v * v;
    #pragma unroll
    for (int m = 1; m < 64; m <<= 1) {
        s  += __shfl_xor(s, m);
        s2 += __shfl_xor(s2, m);
    }
    __shared__ float red[8];
    const int wid = c >> 6;
    if ((c & 63) == 0) { red[wid] = s; red[4 + wid] = s2; }
    __syncthreads();
    const float S  = red[0] + red[1] + red[2] + red[3];
    const float S2 = red[4] + red[5] + red[6] + red[7];
    const float mean = S * (1.0f / 256.0f);
    const float var  = S2 * (1.0f / 256.0f) - mean * mean;
    const float inv  = rsqrtf(var + 1e-6f);
    const float o = (v - mean) * inv * lw[c] + lb[c];
    const int b = r >> 11, ss = r & 2047;
    xf[((size_t)b * 4096 + ss) * 256 + c]        = o;
    xf[((size_t)b * 4096 + 2048 + ss) * 256 + c] = o;
}

// ---------------------------------------------------------------------------
// 3) in_proj: xz[row, j] = sum_c A[row,c] * in_w[dir][j][c]
//    row = (dir*2+b)*4096 + s; dir 1 reads xf reversed. M=16384,K=256,N=1024
// ---------------------------------------------------------------------------
__global__ __launch_bounds__(256) void k_inproj(
    const float* __restrict__ xf, const float* __restrict__ inw,
    float* __restrict__ xz)
{
    __shared__ float sA[32 * LDP];
    __shared__ float sB[32 * LDP];
    const int tid = threadIdx.x;
    const int r0 = blockIdx.x * 64;
    const int n0 = blockIdx.y * 64;
    const int dir = r0 >> 13;
    const int b   = (r0 >> 12) & 1;
    const int tm = tid >> 4, tn = tid & 15;
    const int lm = tid >> 2, lf = tid & 3;
    float acc[4][4] = {};

    const int s_l = (r0 & 4095) + lm;
    const int se  = dir ? (4095 - s_l) : s_l;
    const float* __restrict__ arow = &xf[((size_t)b * 4096 + se) * 256];
    const float* __restrict__ brow = &inw[(size_t)dir * 262144 + (size_t)(n0 + lm) * 256];

    for (int kt = 0; kt < 256; kt += 32) {
        const float4 a1 = *(const float4*)&arow[kt + lf * 4];
        const float4 a2 = *(const float4*)&arow[kt + 16 + lf * 4];
        int kb = lf * 4;
        sA[(kb + 0) * LDP + lm] = a1.x; sA[(kb + 1) * LDP + lm] = a1.y;
        sA[(kb + 2) * LDP + lm] = a1.z; sA[(kb + 3) * LDP + lm] = a1.w;
        kb = 16 + lf * 4;
        sA[(kb + 0) * LDP + lm] = a2.x; sA[(kb + 1) * LDP + lm] = a2.y;
        sA[(kb + 2) * LDP + lm] = a2.z; sA[(kb + 3) * LDP + lm] = a2.w;

        const float4 b1 = *(const float4*)&brow[kt + lf * 4];
        const float4 b2 = *(const float4*)&brow[kt + 16 + lf * 4];
        kb = lf * 4;
        sB[(kb + 0) * LDP + lm] = b1.x; sB[(kb + 1) * LDP + lm] = b1.y;
        sB[(kb + 2) * LDP + lm] = b1.z; sB[(kb + 3) * LDP + lm] = b1.w;
        kb = 16 + lf * 4;
        sB[(kb + 0) * LDP + lm] = b2.x; sB[(kb + 1) * LDP + lm] = b2.y;
        sB[(kb + 2) * LDP + lm] = b2.z; sB[(kb + 3) * LDP + lm] = b2.w;
        __syncthreads();
        #pragma unroll
        for (int k = 0; k < 32; ++k) {
            const float4 av = *(const float4*)&sA[k * LDP + tm * 4];
            const float4 bv = *(const float4*)&sB[k * LDP + tn * 4];
            const float a_[4] = {av.x, av.y, av.z, av.w};
            const float b_[4] = {bv.x, bv.y, bv.z, bv.w};
            #pragma unroll
            for (int i = 0; i < 4; ++i)
                #pragma unroll
                for (int j = 0; j < 4; ++j)
                    acc[i][j] = fmaf(a_[i], b_[j], acc[i][j]);
        }
        __syncthreads();
    }
    #pragma unroll
    for (int i = 0; i < 4; ++i) {
        const size_t r = r0 + tm * 4 + i;
        float4 o = make_float4(acc[i][0], acc[i][1], acc[i][2], acc[i][3]);
        *(float4*)&xz[r * 1024 + n0 + tn * 4] = o;
    }
}

// ---------------------------------------------------------------------------
// 4) causal depthwise conv (K=4) + SiLU -> xc[row, d]
// ---------------------------------------------------------------------------
__global__ __launch_bounds__(256) void k_dwconv(
    const float* __restrict__ xz, const float* __restrict__ cw,
    const float* __restrict__ cb, float* __restrict__ xc)
{
    const int bid = blockIdx.x;       // (dir*2+b)*4096 + s
    const int s  = bid & 4095;
    const int db = bid >> 12;
    const int dir = db >> 1;
    #pragma unroll
    for (int dd = 0; dd < 2; ++dd) {
        const int d = threadIdx.x + dd * 256;
        const float4 wv = *(const float4*)&cw[(size_t)(dir * 512 + d) * 4];
        const float w4[4] = {wv.x, wv.y, wv.z, wv.w};
        float a = cb[dir * 512 + d];
        #pragma unroll
        for (int k = 0; k < 4; ++k) {
            const int sp = s - 3 + k;
            if (sp >= 0)
                a = fmaf(xz[((size_t)db * 4096 + sp) * 1024 + d], w4[k], a);
        }
        xc[((size_t)db * 4096 + s) * 512 + d] = silu_f(a);
    }
}

// ---------------------------------------------------------------------------
// 5) x_proj: xdb[row, j] = sum_d xc[row,d] * xp_w[dir][j][d]   (j<48)
// ---------------------------------------------------------------------------
__global__ __launch_bounds__(256) void k_xdb(
    const float* __restrict__ xc, const float* __restrict__ xpw,
    float* __restrict__ xdb)
{
    __shared__ float sA[32 * LDP];
    __shared__ float sB[32 * LDP];
    const int tid = threadIdx.x;
    const int r0 = blockIdx.x * 64;
    const int dir = r0 >> 13;
    const int tm = tid >> 4, tn = tid & 15;
    const int lm = tid >> 2, lf = tid & 3;
    float acc[4][4] = {};

    const float* __restrict__ arow = &xc[(size_t)(r0 + lm) * 512];
    const int j = lm;
    const float* __restrict__ brow = &xpw[(size_t)dir * 24576 + (size_t)j * 512];

    for (int kt = 0; kt < 512; kt += 32) {
        const float4 a1 = *(const float4*)&arow[kt + lf * 4];
        const float4 a2 = *(const float4*)&arow[kt + 16 + lf * 4];
        int kb = lf * 4;
        sA[(kb + 0) * LDP + lm] = a1.x; sA[(kb + 1) * LDP + lm] = a1.y;
        sA[(kb + 2) * LDP + lm] = a1.z; sA[(kb + 3) * LDP + lm] = a1.w;
        kb = 16 + lf * 4;
        sA[(kb + 0) * LDP + lm] = a2.x; sA[(kb + 1) * LDP + lm] = a2.y;
        sA[(kb + 2) * LDP + lm] = a2.z; sA[(kb + 3) * LDP + lm] = a2.w;

        float4 b1 = make_float4(0.f, 0.f, 0.f, 0.f), b2 = b1;
        if (j < 48) {
            b1 = *(const float4*)&brow[kt + lf * 4];
            b2 = *(const float4*)&brow[kt + 16 + lf * 4];
        }
        kb = lf * 4;
        sB[(kb + 0) * LDP + lm] = b1.x; sB[(kb + 1) * LDP + lm] = b1.y;
        sB[(kb + 2) * LDP + lm] = b1.z; sB[(kb + 3) * LDP + lm] = b1.w;
        kb = 16 + lf * 4;
        sB[(kb + 0) * LDP + lm] = b2.x; sB[(kb + 1) * LDP + lm] = b2.y;
        sB[(kb + 2) * LDP + lm] = b2.z; sB[(kb + 3) * LDP + lm] = b2.w;
        __syncthreads();
        #pragma unroll
        for (int k = 0; k < 32; ++k) {
            const float4 av = *(const float4*)&sA[k * LDP + tm * 4];
            const float4 bv = *(const float4*)&sB[k * LDP + tn * 4];
            const float a_[4] = {av.x, av.y, av.z, av.w};
            const float b_[4] = {bv.x, bv.y, bv.z, bv.w};
            #pragma unroll
            for (int i = 0; i < 4; ++i)
                #pragma unroll
                for (int jj = 0; jj < 4; ++jj)
                    acc[i][jj] = fmaf(a_[i], b_[jj], acc[i][jj]);
        }
        __syncthreads();
    }
    #pragma unroll
    for (int i = 0; i < 4; ++i) {
        const size_t r = r0 + tm * 4 + i;
        #pragma unroll
        for (int jj = 0; jj < 4; ++jj) {
            const int col = tn * 4 + jj;
            if (col < 48) xdb[r * 48 + col] = acc[i][jj];
        }
    }
}

// ---------------------------------------------------------------------------
// 6) dt = softplus(xdb[:, :16] @ dt_w.T + dt_b) -> written into xz[row, d]
//    (the dead xin half of xz)
// ---------------------------------------------------------------------------
__global__ __launch_bounds__(256) void k_dt(
    const float* __restrict__ xdb, const float* __restrict__ dtw,
    const float* __restrict__ dtb, float* __restrict__ xz)
{
    const int row = blockIdx.x;
    const int dir = row >> 13;
    __shared__ float sx[16];
    if (threadIdx.x < 16) sx[threadIdx.x] = xdb[(size_t)row * 48 + threadIdx.x];
    __syncthreads();
    #pragma unroll
    for (int dd = 0; dd < 2; ++dd) {
        const int d = threadIdx.x + dd * 256;
        const float* wp = &dtw[(size_t)(dir * 512 + d) * 16];
        float a = dtb[dir * 512 + d];
        #pragma unroll
        for (int rr = 0; rr < 16; ++rr) a = fmaf(sx[rr], wp[rr], a);
        const float sp = (a > 15.0f) ? a : log1pf(__expf(a));
        xz[(size_t)row * 1024 + d] = sp;
    }
}

// ---------------------------------------------------------------------------
// 7) selective scan. Block = 1 wave = 4 d x 16 n. y overwrites u (in place).
// ---------------------------------------------------------------------------
__global__ __launch_bounds__(64) void k_scan(
    const float* __restrict__ xz,   // dt at [row*1024 + d]
    float* __restrict__ xc,         // u in / y out
    const float* __restrict__ xdb,  // B at [row*48+16+n], C at [row*48+32+n]
    const float* __restrict__ alog,
    const float* __restrict__ dp)
{
    const int bid = blockIdx.x;         // 512 = dir*256 + b*128 + dg
    const int dg  = bid & 127;
    const int b   = (bid >> 7) & 1;
    const int dir = bid >> 8;
    const int lane = threadIdx.x;
    const int n = lane & 15;
    const int d = dg * 4 + (lane >> 4);
    const float Av = -__expf(alog[(size_t)(dir * 512 + d) * 16 + n]);
    const float Dv = dp[dir * 512 + d];
    const int db = dir * 2 + b;
    const float* __restrict__ pdt = xz  + (size_t)db * 4096 * 1024 + d;
    const float* __restrict__ pu  = xc  + (size_t)db * 4096 * 512 + d;
    float*                    py  = xc  + (size_t)db * 4096 * 512 + d;
    const float* __restrict__ pb  = xdb + (size_t)db * 4096 * 48 + 16 + n;
    const float* __restrict__ pc  = xdb + (size_t)db * 4096 * 48 + 32 + n;
    float h = 0.0f;
    const bool wr = (n == 0);
    #pragma unroll 4
    for (int s = 0; s < 4096; ++s) {
        const float dtv = pdt[(size_t)s * 1024];
        const float uv  = pu [(size_t)s * 512];
        const float bv  = pb [(size_t)s * 48];
        const float cv  = pc [(size_t)s * 48];
        const float dA = __expf(dtv * Av);
        h = fmaf(dA, h, dtv * uv * bv);
        float v = h * cv;
        v += __shfl_xor(v, 1);
        v += __shfl_xor(v, 2);
        v += __shfl_xor(v, 4);
        v += __shfl_xor(v, 8);
        if (wr) py[(size_t)s * 512] = fmaf(uv, Dv, v);
    }
}

// ---------------------------------------------------------------------------
// 8) out_proj (both dirs fused): ym[b*4096+s, c] =
//    0.5 * sum_dir sum_d (y*silu(z))[dir, s_eff, d] * out_w[dir][c][d]
// ---------------------------------------------------------------------------
__global__ __launch_bounds__(256) void k_outproj(
    const float* __restrict__ xc,   // y
    const float* __restrict__ xz,   // z at [row*1024 + 512 + d]
    const float* __restrict__ ow,
    float* __restrict__ ym)
{
    __shared__ float sA[32 * LDP];
    __shared__ float sB[32 * LDP];
    const int tid = threadIdx.x;
    const int r0 = blockIdx.x * 64;   // row in [0,8192): b*4096+s
    const int n0 = blockIdx.y * 64;
    const int tm = tid >> 4, tn = tid & 15;
    const int lm = tid >> 2, lf = tid & 3;
    const int rb = r0 + lm;
    const int bb = rb >> 12, s = rb & 4095;
    const int cn = n0 + lm;
    float acc[4][4] = {};

    for (int kt = 0; kt < 1024; kt += 32) {
        const int dir = kt >> 9;
        const int dl  = kt & 511;
        const int se  = dir ? (4095 - s) : s;
        const size_t rowd = (size_t)(dir * 2 + bb) * 4096 + se;
        #pragma unroll
        for (int half = 0; half < 2; ++half) {
            const int off = dl + half * 16 + lf * 4;
            const float4 y4 = *(const float4*)&xc[rowd * 512 + off];
            const float4 z4 = *(const float4*)&xz[rowd * 1024 + 512 + off];
            const int kb = half * 16 + lf * 4;
            sA[(kb + 0) * LDP + lm] = y4.x * silu_f(z4.x);
            sA[(kb + 1) * LDP + lm] = y4.y * silu_f(z4.y);
            sA[(kb + 2) * LDP + lm] = y4.z * silu_f(z4.z);
            sA[(kb + 3) * LDP + lm] = y4.w * silu_f(z4.w);
        }
        {
            const float* bw = &ow[(size_t)dir * 131072 + (size_t)cn * 512 + dl];
            const float4 b1 = *(const float4*)&bw[lf * 4];
            const float4 b2 = *(const float4*)&bw[16 + lf * 4];
            int kb = lf * 4;
            sB[(kb + 0) * LDP + lm] = b1.x; sB[(kb + 1) * LDP + lm] = b1.y;
            sB[(kb + 2) * LDP + lm] = b1.z; sB[(kb + 3) * LDP + lm] = b1.w;
            kb = 16 + lf * 4;
            sB[(kb + 0) * LDP + lm] = b2.x; sB[(kb + 1) * LDP + lm] = b2.y;
            sB[(kb + 2) * LDP + lm] = b2.z; sB[(kb + 3) * LDP + lm] = b2.w;
        }
        __syncthreads();
        #pragma unroll
        for (int k = 0; k < 32; ++k) {
            const float4 av = *(const float4*)&sA[k * LDP + tm * 4];
            const float4 bv = *(const float4*)&sB[k * LDP + tn * 4];
            const float a_[4] = {av.x, av.y, av.z, av.w};
            const float b_[4] = {bv.x, bv.y, bv.z, bv.w};
            #pragma unroll
            for (int i = 0; i < 4; ++i)
                #pragma unroll
                for (int j = 0; j < 4; ++j)
                    acc[i][j] = fmaf(a_[i], b_[j], acc[i][j]);
        }
        __syncthreads();
    }
    #pragma unroll
    for (int i = 0; i < 4; ++i) {
        const size_t r = r0 + tm * 4 + i;
        float4 o = make_float4(0.5f * acc[i][0], 0.5f * acc[i][1],
                               0.5f * acc[i][2], 0.5f * acc[i][3]);
        *(float4*)&ym[r * 256 + n0 + tn * 4] = o;
    }
}

// ---------------------------------------------------------------------------
// 9) assemble 2D maps: s0 = hw-chunk + transposed wh-chunk (and s1)
// ---------------------------------------------------------------------------
__global__ __launch_bounds__(256) void k_assemble(
    const float* __restrict__ ym, float* __restrict__ s0, float* __restrict__ s1)
{
    const int idx = blockIdx.x * 256 + threadIdx.x;   // 0..1048575
    if (idx < 524288) {
        const int j = idx & 31, i = (idx >> 5) & 31, c = (idx >> 10) & 255, b = idx >> 18;
        s0[idx] = ym[((size_t)b * 4096 + i * 32 + j) * 256 + c]
                + ym[((size_t)b * 4096 + 2048 + j * 32 + i) * 256 + c];
    } else {
        const int k = idx - 524288;
        const int j = k & 15, i = (k >> 4) & 63, c = (k >> 10) & 255, b = k >> 18;
        s1[k] = ym[((size_t)b * 4096 + 1024 + i * 16 + j) * 256 + c]
              + ym[((size_t)b * 4096 + 3072 + j * 64 + i) * 256 + c];
    }
}

// ---------------------------------------------------------------------------
// 10) jax bilinear x4 upsample (half-pixel centers, edge clamp)
// ---------------------------------------------------------------------------
__device__ __forceinline__ void bil_idx(int o, int insz, int& i0, int& i1, float& f) {
    const int q = o >> 2, r = o & 3;
    // fractions cycle: r=0:0.625  r=1:0.875  r=2:0.125  r=3:0.375
    f = 0.125f + 0.25f * (float)((r + 2) & 3);
    const int base = q + ((r < 2) ? -1 : 0);
    i0 = base < 0 ? 0 : base;
    i1 = (base + 1 > insz - 1) ? (insz - 1) : (base + 1);
}

__global__ __launch_bounds__(256) void k_upsample(
    const float* __restrict__ s0, const float* __restrict__ s1,
    float* __restrict__ out)
{
    const size_t idx = (size_t)blockIdx.x * 256 + threadIdx.x;
    if (idx < 8388608) {
        const int j = idx & 127, ii = (idx >> 7) & 127;
        const size_t bc = idx >> 14;
        int i0, i1, j0, j1; float fi, fj;
        bil_idx(ii, 32, i0, i1, fi);
        bil_idx(j, 32, j0, j1, fj);
        const float* S = s0 + bc * 1024;
        const float v0 = S[i0 * 32 + j0] * (1.0f - fj) + S[i0 * 32 + j1] * fj;
        const float v1 = S[i1 * 32 + j0] * (1.0f - fj) + S[i1 * 32 + j1] * fj;
        out[idx] = v0 * (1.0f - fi) + v1 * fi;
    } else {
        const size_t k = idx - 8388608;
        const int j = k & 63, ii = (k >> 6) & 255;
        const size_t bc = k >> 14;
        int i0, i1, j0, j1; float fi, fj;
        bil_idx(ii, 64, i0, i1, fi);
        bil_idx(j, 16, j0, j1, fj);
        const float* S = s1 + bc * 1024;
        const float v0 = S[i0 * 16 + j0] * (1.0f - fj) + S[i0 * 16 + j1] * fj;
        const float v1 = S[i1 * 16 + j0] * (1.0f - fj) + S[i1 * 16 + j1] * fj;
        out[idx] = v0 * (1.0f - fi) + v1 * fi;
    }
}

// ---------------------------------------------------------------------------
extern "C" void kernel_launch(void* const* d_in, const int* in_sizes, int n_in,
                              void* d_out, int out_size, void* d_ws, size_t ws_size,
                              hipStream_t stream)
{
    const float* x0   = (const float*)d_in[0];
    const float* x1   = (const float*)d_in[1];
    const float* cw   = (const float*)d_in[2];
    const float* cb   = (const float*)d_in[3];
    const float* lw   = (const float*)d_in[4];
    const float* lb   = (const float*)d_in[5];
    const float* inw  = (const float*)d_in[6];
    const float* c1w  = (const float*)d_in[7];
    const float* c1b  = (const float*)d_in[8];
    const float* xpw  = (const float*)d_in[9];
    const float* dtw  = (const float*)d_in[10];
    const float* dtb  = (const float*)d_in[11];
    const float* alog = (const float*)d_in[12];
    const float* dp   = (const float*)d_in[13];
    const float* ow   = (const float*)d_in[14];

    float* ws  = (float*)d_ws;
    // phase-1 buffers
    float* dcn = ws;                 // 1,048,576 f
    float* xf  = ws + 1048576;       // 2,097,152 f
    float* xz  = ws + 3145728;       // 16,777,216 f  (xin | z; xin half reused for dt)
    float* xc  = ws + 19922944;      // 8,388,608 f   (xc, then y in place)
    float* xdb = ws + 28311552;      //   786,432 f
    // phase-2 aliases over dead dcn/xf
    float* ym  = ws;                 // 2,097,152 f
    float* s0m = ws + 2097152;       //   524,288 f
    float* s1m = ws + 2621440;       //   524,288 f
    float* out = (float*)d_out;

    k_down    <<<dim3(64, 4),   256, 0, stream>>>(x0, x1, cw, cb, dcn);
    k_ln      <<<4096,          256, 0, stream>>>(dcn, lw, lb, xf);
    k_inproj  <<<dim3(256, 16), 256, 0, stream>>>(xf, inw, xz);
    k_dwconv  <<<16384,         256, 0, stream>>>(xz, c1w, c1b, xc);
    k_xdb     <<<256,           256, 0, stream>>>(xc, xpw, xdb);
    k_dt      <<<16384,         256, 0, stream>>>(xdb, dtw, dtb, xz);
    k_scan    <<<512,           64,  0, stream>>>(xz, xc, xdb, alog, dp);
    k_outproj <<<dim3(128, 4),  256, 0, stream>>>(xc, xz, ow, ym);
    k_assemble<<<4096,          256, 0, stream>>>(ym, s0m, s1m);
    k_upsample<<<65536,         256, 0, stream>>>(s0m, s1m, out);
}

// Round 2
// 836.872 us; speedup vs baseline: 2.9116x; 2.9116x over previous
//
#include <hip/hip_runtime.h>
#include <math.h>

#define LDP 68   // padded LDS leading dim for 64-wide tiles (68*4B row stride, 16B-aligned)

#define SCAN_NC 32
#define SCAN_L  128

__device__ __forceinline__ float silu_f(float x) {
    return x * (1.0f / (1.0f + __expf(-x)));
}

// ---------------------------------------------------------------------------
// 1) Down conv as patch GEMM: dcn[r, co], r = b*2048 + img*1024 + p
//    M=4096, K=4096 (ci*16 + kh*4 + kw), N=256
// ---------------------------------------------------------------------------
__global__ __launch_bounds__(256) void k_down(
    const float* __restrict__ x0, const float* __restrict__ x1,
    const float* __restrict__ w, const float* __restrict__ bias,
    float* __restrict__ dcn)
{
    __shared__ float sA[32 * LDP];
    __shared__ float sB[32 * LDP];
    const int tid = threadIdx.x;
    const int mb = blockIdx.x, nb = blockIdx.y;
    const int r0 = mb * 64;
    const int b   = r0 >> 11;
    const int img = (r0 >> 10) & 1;
    const int p0  = r0 & 1023;
    const float* __restrict__ xs = img ? x1 : x0;
    const int H = img ? 256 : 128;
    const int W = img ? 64 : 128;
    const int pwsh   = img ? 4 : 5;
    const int pwmask = img ? 15 : 31;

    const int tm = tid >> 4, tn = tid & 15;
    const int lm = tid >> 3;
    const int lf = tid & 7;
    const int ci_off = lf >> 2, kh = lf & 3;
    const int lco = tid >> 2;
    const int lbf = tid & 3;

    float acc[4][4] = {};

    for (int kt = 0; kt < 4096; kt += 32) {
        const int ci = (kt >> 4) + ci_off;
        #pragma unroll
        for (int rr = 0; rr < 2; ++rr) {
            const int m = lm + rr * 32;
            const int p = p0 + m;
            const int ph = p >> pwsh;
            const int pw = p & pwmask;
            const float4 v = *(const float4*)&xs[(size_t)(((b * 256 + ci) * H + ph * 4 + kh) * W) + pw * 4];
            const int kb = ci_off * 16 + kh * 4;
            sA[(kb + 0) * LDP + m] = v.x;
            sA[(kb + 1) * LDP + m] = v.y;
            sA[(kb + 2) * LDP + m] = v.z;
            sA[(kb + 3) * LDP + m] = v.w;
        }
        {
            const int co = nb * 64 + lco;
            const float4 w1 = *(const float4*)&w[(size_t)co * 4096 + kt + lbf * 4];
            const float4 w2 = *(const float4*)&w[(size_t)co * 4096 + kt + 16 + lbf * 4];
            int kb = lbf * 4;
            sB[(kb + 0) * LDP + lco] = w1.x; sB[(kb + 1) * LDP + lco] = w1.y;
            sB[(kb + 2) * LDP + lco] = w1.z; sB[(kb + 3) * LDP + lco] = w1.w;
            kb = 16 + lbf * 4;
            sB[(kb + 0) * LDP + lco] = w2.x; sB[(kb + 1) * LDP + lco] = w2.y;
            sB[(kb + 2) * LDP + lco] = w2.z; sB[(kb + 3) * LDP + lco] = w2.w;
        }
        __syncthreads();
        #pragma unroll
        for (int k = 0; k < 32; ++k) {
            const float4 av = *(const float4*)&sA[k * LDP + tm * 4];
            const float4 bv = *(const float4*)&sB[k * LDP + tn * 4];
            const float a_[4] = {av.x, av.y, av.z, av.w};
            const float b_[4] = {bv.x, bv.y, bv.z, bv.w};
            #pragma unroll
            for (int i = 0; i < 4; ++i)
                #pragma unroll
                for (int j = 0; j < 4; ++j)
                    acc[i][j] = fmaf(a_[i], b_[j], acc[i][j]);
        }
        __syncthreads();
    }
    #pragma unroll
    for (int i = 0; i < 4; ++i) {
        const int r = r0 + tm * 4 + i;
        #pragma unroll
        for (int j = 0; j < 4; ++j) {
            const int co = nb * 64 + tn * 4 + j;
            dcn[(size_t)r * 256 + co] = acc[i][j] + bias[co];
        }
    }
}

// ---------------------------------------------------------------------------
// 2) LayerNorm over C per position; writes sequence xf[b, s, c] twice
// ---------------------------------------------------------------------------
__global__ __launch_bounds__(256) void k_ln(
    const float* __restrict__ dcn, const float* __restrict__ lw,
    const float* __restrict__ lb, float* __restrict__ xf)
{
    const int r = blockIdx.x;      // b*2048 + img*1024 + p
    const int c = threadIdx.x;
    const float v = dcn[(size_t)r * 256 + c];
    float s = v, s2 = v * v;
    #pragma unroll
    for (int m = 1; m < 64; m <<= 1) {
        s  += __shfl_xor(s, m);
        s2 += __shfl_xor(s2, m);
    }
    __shared__ float red[8];
    const int wid = c >> 6;
    if ((c & 63) == 0) { red[wid] = s; red[4 + wid] = s2; }
    __syncthreads();
    const float S  = red[0] + red[1] + red[2] + red[3];
    const float S2 = red[4] + red[5] + red[6] + red[7];
    const float mean = S * (1.0f / 256.0f);
    const float var  = S2 * (1.0f / 256.0f) - mean * mean;
    const float inv  = rsqrtf(var + 1e-6f);
    const float o = (v - mean) * inv * lw[c] + lb[c];
    const int b = r >> 11, ss = r & 2047;
    xf[((size_t)b * 4096 + ss) * 256 + c]        = o;
    xf[((size_t)b * 4096 + 2048 + ss) * 256 + c] = o;
}

// ---------------------------------------------------------------------------
// 3) in_proj: M=16384, K=256, N=1024; dir 1 reads xf reversed
// ---------------------------------------------------------------------------
__global__ __launch_bounds__(256) void k_inproj(
    const float* __restrict__ xf, const float* __restrict__ inw,
    float* __restrict__ xz)
{
    __shared__ float sA[32 * LDP];
    __shared__ float sB[32 * LDP];
    const int tid = threadIdx.x;
    const int r0 = blockIdx.x * 64;
    const int n0 = blockIdx.y * 64;
    const int dir = r0 >> 13;
    const int b   = (r0 >> 12) & 1;
    const int tm = tid >> 4, tn = tid & 15;
    const int lm = tid >> 2, lf = tid & 3;
    float acc[4][4] = {};

    const int s_l = (r0 & 4095) + lm;
    const int se  = dir ? (4095 - s_l) : s_l;
    const float* __restrict__ arow = &xf[((size_t)b * 4096 + se) * 256];
    const float* __restrict__ brow = &inw[(size_t)dir * 262144 + (size_t)(n0 + lm) * 256];

    for (int kt = 0; kt < 256; kt += 32) {
        const float4 a1 = *(const float4*)&arow[kt + lf * 4];
        const float4 a2 = *(const float4*)&arow[kt + 16 + lf * 4];
        int kb = lf * 4;
        sA[(kb + 0) * LDP + lm] = a1.x; sA[(kb + 1) * LDP + lm] = a1.y;
        sA[(kb + 2) * LDP + lm] = a1.z; sA[(kb + 3) * LDP + lm] = a1.w;
        kb = 16 + lf * 4;
        sA[(kb + 0) * LDP + lm] = a2.x; sA[(kb + 1) * LDP + lm] = a2.y;
        sA[(kb + 2) * LDP + lm] = a2.z; sA[(kb + 3) * LDP + lm] = a2.w;

        const float4 b1 = *(const float4*)&brow[kt + lf * 4];
        const float4 b2 = *(const float4*)&brow[kt + 16 + lf * 4];
        kb = lf * 4;
        sB[(kb + 0) * LDP + lm] = b1.x; sB[(kb + 1) * LDP + lm] = b1.y;
        sB[(kb + 2) * LDP + lm] = b1.z; sB[(kb + 3) * LDP + lm] = b1.w;
        kb = 16 + lf * 4;
        sB[(kb + 0) * LDP + lm] = b2.x; sB[(kb + 1) * LDP + lm] = b2.y;
        sB[(kb + 2) * LDP + lm] = b2.z; sB[(kb + 3) * LDP + lm] = b2.w;
        __syncthreads();
        #pragma unroll
        for (int k = 0; k < 32; ++k) {
            const float4 av = *(const float4*)&sA[k * LDP + tm * 4];
            const float4 bv = *(const float4*)&sB[k * LDP + tn * 4];
            const float a_[4] = {av.x, av.y, av.z, av.w};
            const float b_[4] = {bv.x, bv.y, bv.z, bv.w};
            #pragma unroll
            for (int i = 0; i < 4; ++i)
                #pragma unroll
                for (int j = 0; j < 4; ++j)
                    acc[i][j] = fmaf(a_[i], b_[j], acc[i][j]);
        }
        __syncthreads();
    }
    #pragma unroll
    for (int i = 0; i < 4; ++i) {
        const size_t r = r0 + tm * 4 + i;
        float4 o = make_float4(acc[i][0], acc[i][1], acc[i][2], acc[i][3]);
        *(float4*)&xz[r * 1024 + n0 + tn * 4] = o;
    }
}

// ---------------------------------------------------------------------------
// 4) causal depthwise conv (K=4) + SiLU -> xc[row, d]
// ---------------------------------------------------------------------------
__global__ __launch_bounds__(256) void k_dwconv(
    const float* __restrict__ xz, const float* __restrict__ cw,
    const float* __restrict__ cb, float* __restrict__ xc)
{
    const int bid = blockIdx.x;       // (dir*2+b)*4096 + s
    const int s  = bid & 4095;
    const int db = bid >> 12;
    const int dir = db >> 1;
    #pragma unroll
    for (int dd = 0; dd < 2; ++dd) {
        const int d = threadIdx.x + dd * 256;
        const float4 wv = *(const float4*)&cw[(size_t)(dir * 512 + d) * 4];
        const float w4[4] = {wv.x, wv.y, wv.z, wv.w};
        float a = cb[dir * 512 + d];
        #pragma unroll
        for (int k = 0; k < 4; ++k) {
            const int sp = s - 3 + k;
            if (sp >= 0)
                a = fmaf(xz[((size_t)db * 4096 + sp) * 1024 + d], w4[k], a);
        }
        xc[((size_t)db * 4096 + s) * 512 + d] = silu_f(a);
    }
}

// ---------------------------------------------------------------------------
// 5) x_proj: xdb[row, j] = sum_d xc[row,d] * xp_w[dir][j][d]   (j<48)
// ---------------------------------------------------------------------------
__global__ __launch_bounds__(256) void k_xdb(
    const float* __restrict__ xc, const float* __restrict__ xpw,
    float* __restrict__ xdb)
{
    __shared__ float sA[32 * LDP];
    __shared__ float sB[32 * LDP];
    const int tid = threadIdx.x;
    const int r0 = blockIdx.x * 64;
    const int dir = r0 >> 13;
    const int tm = tid >> 4, tn = tid & 15;
    const int lm = tid >> 2, lf = tid & 3;
    float acc[4][4] = {};

    const float* __restrict__ arow = &xc[(size_t)(r0 + lm) * 512];
    const int j = lm;
    const float* __restrict__ brow = &xpw[(size_t)dir * 24576 + (size_t)j * 512];

    for (int kt = 0; kt < 512; kt += 32) {
        const float4 a1 = *(const float4*)&arow[kt + lf * 4];
        const float4 a2 = *(const float4*)&arow[kt + 16 + lf * 4];
        int kb = lf * 4;
        sA[(kb + 0) * LDP + lm] = a1.x; sA[(kb + 1) * LDP + lm] = a1.y;
        sA[(kb + 2) * LDP + lm] = a1.z; sA[(kb + 3) * LDP + lm] = a1.w;
        kb = 16 + lf * 4;
        sA[(kb + 0) * LDP + lm] = a2.x; sA[(kb + 1) * LDP + lm] = a2.y;
        sA[(kb + 2) * LDP + lm] = a2.z; sA[(kb + 3) * LDP + lm] = a2.w;

        float4 b1 = make_float4(0.f, 0.f, 0.f, 0.f), b2 = b1;
        if (j < 48) {
            b1 = *(const float4*)&brow[kt + lf * 4];
            b2 = *(const float4*)&brow[kt + 16 + lf * 4];
        }
        kb = lf * 4;
        sB[(kb + 0) * LDP + lm] = b1.x; sB[(kb + 1) * LDP + lm] = b1.y;
        sB[(kb + 2) * LDP + lm] = b1.z; sB[(kb + 3) * LDP + lm] = b1.w;
        kb = 16 + lf * 4;
        sB[(kb + 0) * LDP + lm] = b2.x; sB[(kb + 1) * LDP + lm] = b2.y;
        sB[(kb + 2) * LDP + lm] = b2.z; sB[(kb + 3) * LDP + lm] = b2.w;
        __syncthreads();
        #pragma unroll
        for (int k = 0; k < 32; ++k) {
            const float4 av = *(const float4*)&sA[k * LDP + tm * 4];
            const float4 bv = *(const float4*)&sB[k * LDP + tn * 4];
            const float a_[4] = {av.x, av.y, av.z, av.w};
            const float b_[4] = {bv.x, bv.y, bv.z, bv.w};
            #pragma unroll
            for (int i = 0; i < 4; ++i)
                #pragma unroll
                for (int jj = 0; jj < 4; ++jj)
                    acc[i][jj] = fmaf(a_[i], b_[jj], acc[i][jj]);
        }
        __syncthreads();
    }
    #pragma unroll
    for (int i = 0; i < 4; ++i) {
        const size_t r = r0 + tm * 4 + i;
        #pragma unroll
        for (int jj = 0; jj < 4; ++jj) {
            const int col = tn * 4 + jj;
            if (col < 48) xdb[r * 48 + col] = acc[i][jj];
        }
    }
}

// ---------------------------------------------------------------------------
// 6) dt = softplus(xdb[:, :16] @ dt_w.T + dt_b) -> xz xin half (dead)
// ---------------------------------------------------------------------------
__global__ __launch_bounds__(256) void k_dt(
    const float* __restrict__ xdb, const float* __restrict__ dtw,
    const float* __restrict__ dtb, float* __restrict__ xz)
{
    const int row = blockIdx.x;
    const int dir = row >> 13;
    __shared__ float sx[16];
    if (threadIdx.x < 16) sx[threadIdx.x] = xdb[(size_t)row * 48 + threadIdx.x];
    __syncthreads();
    #pragma unroll
    for (int dd = 0; dd < 2; ++dd) {
        const int d = threadIdx.x + dd * 256;
        const float* wp = &dtw[(size_t)(dir * 512 + d) * 16];
        float a = dtb[dir * 512 + d];
        #pragma unroll
        for (int rr = 0; rr < 16; ++rr) a = fmaf(sx[rr], wp[rr], a);
        const float sp = (a > 15.0f) ? a : log1pf(__expf(a));
        xz[(size_t)row * 1024 + d] = sp;
    }
}

// ---------------------------------------------------------------------------
// 7a) scan pass A: per-chunk summaries. 16 n-states per thread (thread = d).
//     blk = db*64 + c*2 + half; 256 thr; d = half*256 + tid.
// ---------------------------------------------------------------------------
__global__ __launch_bounds__(256) void k_scan_a(
    const float* __restrict__ xz,   // dt at [row*1024 + d]
    const float* __restrict__ xc,   // u
    const float* __restrict__ xdb,  // B at [row*48 + 16 + n]
    const float* __restrict__ alog,
    float* __restrict__ hsum, float* __restrict__ aprod)
{
    __shared__ float sB[SCAN_L * 16];
    const int blk  = blockIdx.x;
    const int half = blk & 1;
    const int c    = (blk >> 1) & 31;
    const int db   = blk >> 6;
    const int dir  = db >> 1;
    const int d    = half * 256 + threadIdx.x;
    const int s0   = c * SCAN_L;

    for (int i = threadIdx.x; i < SCAN_L * 16; i += 256) {
        const int sl = i >> 4, j = i & 15;
        sB[i] = xdb[((size_t)db * 4096 + s0 + sl) * 48 + 16 + j];
    }
    float Av[16];
    #pragma unroll
    for (int n = 0; n < 16; ++n)
        Av[n] = -__expf(alog[(size_t)(dir * 512 + d) * 16 + n]) * 1.44269504f;
    __syncthreads();

    float h[16] = {};
    float P[16];
    #pragma unroll
    for (int n = 0; n < 16; ++n) P[n] = 1.0f;

    const float* __restrict__ pdt = xz + ((size_t)db * 4096 + s0) * 1024 + d;
    const float* __restrict__ pu  = xc + ((size_t)db * 4096 + s0) * 512 + d;
    float dtn = pdt[0], un = pu[0];
    for (int s = 0; s < SCAN_L; ++s) {
        const float dtc = dtn, uc = un;
        if (s + 1 < SCAN_L) {
            dtn = pdt[(size_t)(s + 1) * 1024];
            un  = pu[(size_t)(s + 1) * 512];
        }
        const float dtu = dtc * uc;
        const float4 b0 = *(const float4*)&sB[s * 16 + 0];
        const float4 b1 = *(const float4*)&sB[s * 16 + 4];
        const float4 b2 = *(const float4*)&sB[s * 16 + 8];
        const float4 b3 = *(const float4*)&sB[s * 16 + 12];
        const float bb[16] = {b0.x,b0.y,b0.z,b0.w, b1.x,b1.y,b1.z,b1.w,
                              b2.x,b2.y,b2.z,b2.w, b3.x,b3.y,b3.z,b3.w};
        #pragma unroll
        for (int n = 0; n < 16; ++n) {
            const float dA = exp2f(dtc * Av[n]);
            h[n] = fmaf(dA, h[n], dtu * bb[n]);
            P[n] *= dA;
        }
    }
    float* hs = hsum  + (size_t)c * 32768 + (size_t)db * 8192 + (size_t)d * 16;
    float* ap = aprod + (size_t)c * 32768 + (size_t)db * 8192 + (size_t)d * 16;
    #pragma unroll
    for (int n = 0; n < 16; n += 4) {
        *(float4*)&hs[n] = make_float4(h[n], h[n+1], h[n+2], h[n+3]);
        *(float4*)&ap[n] = make_float4(P[n], P[n+1], P[n+2], P[n+3]);
    }
}

// ---------------------------------------------------------------------------
// 7b) scan pass B: combine chunk summaries; hsum becomes h_init per chunk.
// ---------------------------------------------------------------------------
__global__ __launch_bounds__(256) void k_scan_b(
    float* __restrict__ hsum, const float* __restrict__ aprod)
{
    const int t = blockIdx.x * 256 + threadIdx.x;   // 0..32767
    float h = 0.0f;
    for (int c = 0; c < SCAN_NC; ++c) {
        const float tmp = hsum[(size_t)c * 32768 + t];
        const float p   = aprod[(size_t)c * 32768 + t];
        hsum[(size_t)c * 32768 + t] = h;
        h = fmaf(p, h, tmp);
    }
}

// ---------------------------------------------------------------------------
// 7c) scan pass C: full scan from h_init, y overwrites u in place.
// ---------------------------------------------------------------------------
__global__ __launch_bounds__(256) void k_scan_c(
    const float* __restrict__ xz,    // dt
    float* __restrict__ xc,          // u in / y out
    const float* __restrict__ xdb,   // B,C at [row*48 + 16..47]
    const float* __restrict__ alog,
    const float* __restrict__ dp,
    const float* __restrict__ hinit)
{
    __shared__ float sBC[SCAN_L * 32];
    const int blk  = blockIdx.x;
    const int half = blk & 1;
    const int c    = (blk >> 1) & 31;
    const int db   = blk >> 6;
    const int dir  = db >> 1;
    const int d    = half * 256 + threadIdx.x;
    const int s0   = c * SCAN_L;

    for (int i = threadIdx.x; i < SCAN_L * 32; i += 256) {
        const int sl = i >> 5, j = i & 31;
        sBC[i] = xdb[((size_t)db * 4096 + s0 + sl) * 48 + 16 + j];
    }
    float Av[16];
    #pragma unroll
    for (int n = 0; n < 16; ++n)
        Av[n] = -__expf(alog[(size_t)(dir * 512 + d) * 16 + n]) * 1.44269504f;
    const float Dv = dp[dir * 512 + d];

    float h[16];
    const float* hi = hinit + (size_t)c * 32768 + (size_t)db * 8192 + (size_t)d * 16;
    #pragma unroll
    for (int n = 0; n < 16; n += 4) {
        const float4 v = *(const float4*)&hi[n];
        h[n] = v.x; h[n+1] = v.y; h[n+2] = v.z; h[n+3] = v.w;
    }
    __syncthreads();

    const float* __restrict__ pdt = xz + ((size_t)db * 4096 + s0) * 1024 + d;
    float*                    pu  = xc + ((size_t)db * 4096 + s0) * 512 + d;
    float dtn = pdt[0], un = pu[0];
    for (int s = 0; s < SCAN_L; ++s) {
        const float dtc = dtn, uc = un;
        if (s + 1 < SCAN_L) {
            dtn = pdt[(size_t)(s + 1) * 1024];
            un  = pu[(size_t)(s + 1) * 512];
        }
        const float dtu = dtc * uc;
        const float4 b0 = *(const float4*)&sBC[s * 32 + 0];
        const float4 b1 = *(const float4*)&sBC[s * 32 + 4];
        const float4 b2 = *(const float4*)&sBC[s * 32 + 8];
        const float4 b3 = *(const float4*)&sBC[s * 32 + 12];
        const float4 c0 = *(const float4*)&sBC[s * 32 + 16];
        const float4 c1 = *(const float4*)&sBC[s * 32 + 20];
        const float4 c2 = *(const float4*)&sBC[s * 32 + 24];
        const float4 c3 = *(const float4*)&sBC[s * 32 + 28];
        const float bb[16] = {b0.x,b0.y,b0.z,b0.w, b1.x,b1.y,b1.z,b1.w,
                              b2.x,b2.y,b2.z,b2.w, b3.x,b3.y,b3.z,b3.w};
        const float cc[16] = {c0.x,c0.y,c0.z,c0.w, c1.x,c1.y,c1.z,c1.w,
                              c2.x,c2.y,c2.z,c2.w, c3.x,c3.y,c3.z,c3.w};
        float y0 = 0.f, y1 = 0.f, y2 = 0.f, y3 = 0.f;
        #pragma unroll
        for (int n = 0; n < 16; n += 4) {
            const float dA0 = exp2f(dtc * Av[n+0]);
            const float dA1 = exp2f(dtc * Av[n+1]);
            const float dA2 = exp2f(dtc * Av[n+2]);
            const float dA3 = exp2f(dtc * Av[n+3]);
            h[n+0] = fmaf(dA0, h[n+0], dtu * bb[n+0]);
            h[n+1] = fmaf(dA1, h[n+1], dtu * bb[n+1]);
            h[n+2] = fmaf(dA2, h[n+2], dtu * bb[n+2]);
            h[n+3] = fmaf(dA3, h[n+3], dtu * bb[n+3]);
            y0 = fmaf(h[n+0], cc[n+0], y0);
            y1 = fmaf(h[n+1], cc[n+1], y1);
            y2 = fmaf(h[n+2], cc[n+2], y2);
            y3 = fmaf(h[n+3], cc[n+3], y3);
        }
        pu[(size_t)s * 512] = fmaf(uc, Dv, (y0 + y1) + (y2 + y3));
    }
}

// ---------------------------------------------------------------------------
// 8) out_proj (both dirs fused)
// ---------------------------------------------------------------------------
__global__ __launch_bounds__(256) void k_outproj(
    const float* __restrict__ xc,   // y
    const float* __restrict__ xz,   // z at [row*1024 + 512 + d]
    const float* __restrict__ ow,
    float* __restrict__ ym)
{
    __shared__ float sA[32 * LDP];
    __shared__ float sB[32 * LDP];
    const int tid = threadIdx.x;
    const int r0 = blockIdx.x * 64;   // row in [0,8192): b*4096+s
    const int n0 = blockIdx.y * 64;
    const int tm = tid >> 4, tn = tid & 15;
    const int lm = tid >> 2, lf = tid & 3;
    const int rb = r0 + lm;
    const int bb = rb >> 12, s = rb & 4095;
    const int cn = n0 + lm;
    float acc[4][4] = {};

    for (int kt = 0; kt < 1024; kt += 32) {
        const int dir = kt >> 9;
        const int dl  = kt & 511;
        const int se  = dir ? (4095 - s) : s;
        const size_t rowd = (size_t)(dir * 2 + bb) * 4096 + se;
        #pragma unroll
        for (int half = 0; half < 2; ++half) {
            const int off = dl + half * 16 + lf * 4;
            const float4 y4 = *(const float4*)&xc[rowd * 512 + off];
            const float4 z4 = *(const float4*)&xz[rowd * 1024 + 512 + off];
            const int kb = half * 16 + lf * 4;
            sA[(kb + 0) * LDP + lm] = y4.x * silu_f(z4.x);
            sA[(kb + 1) * LDP + lm] = y4.y * silu_f(z4.y);
            sA[(kb + 2) * LDP + lm] = y4.z * silu_f(z4.z);
            sA[(kb + 3) * LDP + lm] = y4.w * silu_f(z4.w);
        }
        {
            const float* bw = &ow[(size_t)dir * 131072 + (size_t)cn * 512 + dl];
            const float4 b1 = *(const float4*)&bw[lf * 4];
            const float4 b2 = *(const float4*)&bw[16 + lf * 4];
            int kb = lf * 4;
            sB[(kb + 0) * LDP + lm] = b1.x; sB[(kb + 1) * LDP + lm] = b1.y;
            sB[(kb + 2) * LDP + lm] = b1.z; sB[(kb + 3) * LDP + lm] = b1.w;
            kb = 16 + lf * 4;
            sB[(kb + 0) * LDP + lm] = b2.x; sB[(kb + 1) * LDP + lm] = b2.y;
            sB[(kb + 2) * LDP + lm] = b2.z; sB[(kb + 3) * LDP + lm] = b2.w;
        }
        __syncthreads();
        #pragma unroll
        for (int k = 0; k < 32; ++k) {
            const float4 av = *(const float4*)&sA[k * LDP + tm * 4];
            const float4 bv = *(const float4*)&sB[k * LDP + tn * 4];
            const float a_[4] = {av.x, av.y, av.z, av.w};
            const float b_[4] = {bv.x, bv.y, bv.z, bv.w};
            #pragma unroll
            for (int i = 0; i < 4; ++i)
                #pragma unroll
                for (int j = 0; j < 4; ++j)
                    acc[i][j] = fmaf(a_[i], b_[j], acc[i][j]);
        }
        __syncthreads();
    }
    #pragma unroll
    for (int i = 0; i < 4; ++i) {
        const size_t r = r0 + tm * 4 + i;
        float4 o = make_float4(0.5f * acc[i][0], 0.5f * acc[i][1],
                               0.5f * acc[i][2], 0.5f * acc[i][3]);
        *(float4*)&ym[r * 256 + n0 + tn * 4] = o;
    }
}

// ---------------------------------------------------------------------------
// 9) assemble 2D maps
// ---------------------------------------------------------------------------
__global__ __launch_bounds__(256) void k_assemble(
    const float* __restrict__ ym, float* __restrict__ s0, float* __restrict__ s1)
{
    const int idx = blockIdx.x * 256 + threadIdx.x;   // 0..1048575
    if (idx < 524288) {
        const int j = idx & 31, i = (idx >> 5) & 31, c = (idx >> 10) & 255, b = idx >> 18;
        s0[idx] = ym[((size_t)b * 4096 + i * 32 + j) * 256 + c]
                + ym[((size_t)b * 4096 + 2048 + j * 32 + i) * 256 + c];
    } else {
        const int k = idx - 524288;
        const int j = k & 15, i = (k >> 4) & 63, c = (k >> 10) & 255, b = k >> 18;
        s1[k] = ym[((size_t)b * 4096 + 1024 + i * 16 + j) * 256 + c]
              + ym[((size_t)b * 4096 + 3072 + j * 64 + i) * 256 + c];
    }
}

// ---------------------------------------------------------------------------
// 10) jax bilinear x4 upsample
// ---------------------------------------------------------------------------
__device__ __forceinline__ void bil_idx(int o, int insz, int& i0, int& i1, float& f) {
    const int q = o >> 2, r = o & 3;
    f = 0.125f + 0.25f * (float)((r + 2) & 3);
    const int base = q + ((r < 2) ? -1 : 0);
    i0 = base < 0 ? 0 : base;
    i1 = (base + 1 > insz - 1) ? (insz - 1) : (base + 1);
}

__global__ __launch_bounds__(256) void k_upsample(
    const float* __restrict__ s0, const float* __restrict__ s1,
    float* __restrict__ out)
{
    const size_t idx = (size_t)blockIdx.x * 256 + threadIdx.x;
    if (idx < 8388608) {
        const int j = idx & 127, ii = (idx >> 7) & 127;
        const size_t bc = idx >> 14;
        int i0, i1, j0, j1; float fi, fj;
        bil_idx(ii, 32, i0, i1, fi);
        bil_idx(j, 32, j0, j1, fj);
        const float* S = s0 + bc * 1024;
        const float v0 = S[i0 * 32 + j0] * (1.0f - fj) + S[i0 * 32 + j1] * fj;
        const float v1 = S[i1 * 32 + j0] * (1.0f - fj) + S[i1 * 32 + j1] * fj;
        out[idx] = v0 * (1.0f - fi) + v1 * fi;
    } else {
        const size_t k = idx - 8388608;
        const int j = k & 63, ii = (k >> 6) & 255;
        const size_t bc = k >> 14;
        int i0, i1, j0, j1; float fi, fj;
        bil_idx(ii, 64, i0, i1, fi);
        bil_idx(j, 16, j0, j1, fj);
        const float* S = s1 + bc * 1024;
        const float v0 = S[i0 * 16 + j0] * (1.0f - fj) + S[i0 * 16 + j1] * fj;
        const float v1 = S[i1 * 16 + j0] * (1.0f - fj) + S[i1 * 16 + j1] * fj;
        out[idx] = v0 * (1.0f - fi) + v1 * fi;
    }
}

// ---------------------------------------------------------------------------
extern "C" void kernel_launch(void* const* d_in, const int* in_sizes, int n_in,
                              void* d_out, int out_size, void* d_ws, size_t ws_size,
                              hipStream_t stream)
{
    const float* x0   = (const float*)d_in[0];
    const float* x1   = (const float*)d_in[1];
    const float* cw   = (const float*)d_in[2];
    const float* cb   = (const float*)d_in[3];
    const float* lw   = (const float*)d_in[4];
    const float* lb   = (const float*)d_in[5];
    const float* inw  = (const float*)d_in[6];
    const float* c1w  = (const float*)d_in[7];
    const float* c1b  = (const float*)d_in[8];
    const float* xpw  = (const float*)d_in[9];
    const float* dtw  = (const float*)d_in[10];
    const float* dtb  = (const float*)d_in[11];
    const float* alog = (const float*)d_in[12];
    const float* dp   = (const float*)d_in[13];
    const float* ow   = (const float*)d_in[14];

    float* ws  = (float*)d_ws;
    // phase-1 buffers
    float* dcn = ws;                 // 1,048,576 f (dead after k_ln)
    float* xf  = ws + 1048576;       // 2,097,152 f (dead after k_inproj)
    float* xz  = ws + 3145728;       // 16,777,216 f  (xin | z; xin half reused for dt)
    float* xc  = ws + 19922944;      // 8,388,608 f   (xc, then y in place)
    float* xdb = ws + 28311552;      //   786,432 f
    // scan summaries alias dead dcn/xf: 2 x 1,048,576 f
    float* hsum  = ws;               // SCAN_NC*32768 = 1,048,576 f
    float* aprod = ws + 1048576;     // 1,048,576 f
    // phase-2 aliases (after scan)
    float* ym  = ws;                 // 2,097,152 f
    float* s0m = ws + 2097152;       //   524,288 f
    float* s1m = ws + 2621440;       //   524,288 f
    float* out = (float*)d_out;

    k_down    <<<dim3(64, 4),   256, 0, stream>>>(x0, x1, cw, cb, dcn);
    k_ln      <<<4096,          256, 0, stream>>>(dcn, lw, lb, xf);
    k_inproj  <<<dim3(256, 16), 256, 0, stream>>>(xf, inw, xz);
    k_dwconv  <<<16384,         256, 0, stream>>>(xz, c1w, c1b, xc);
    k_xdb     <<<256,           256, 0, stream>>>(xc, xpw, xdb);
    k_dt      <<<16384,         256, 0, stream>>>(xdb, dtw, dtb, xz);
    k_scan_a  <<<256,           256, 0, stream>>>(xz, xc, xdb, alog, hsum, aprod);
    k_scan_b  <<<128,           256, 0, stream>>>(hsum, aprod);
    k_scan_c  <<<256,           256, 0, stream>>>(xz, xc, xdb, alog, dp, hsum);
    k_outproj <<<dim3(128, 4),  256, 0, stream>>>(xc, xz, ow, ym);
    k_assemble<<<4096,          256, 0, stream>>>(ym, s0m, s1m);
    k_upsample<<<65536,         256, 0, stream>>>(s0m, s1m, out);
}

// Round 3
// 564.350 us; speedup vs baseline: 4.3176x; 1.4829x over previous
//
#include <hip/hip_runtime.h>
#include <math.h>

#define LDP 68   // padded LDS leading dim for fp32 64-wide tiles
#define SAP 40   // padded LDS row stride (shorts) for bf16 32-k tiles (+8 pad)

#define SCAN_NC 32
#define SCAN_L  128

typedef __attribute__((ext_vector_type(8))) short bf16x8;
typedef __attribute__((ext_vector_type(4))) float f32x4;

__device__ __forceinline__ float silu_f(float x) {
    return x * (1.0f / (1.0f + __expf(-x)));
}
__device__ __forceinline__ short f2bf(float f) {   // RNE float->bf16 (finite inputs)
    unsigned u = __float_as_uint(f);
    u += 0x7fff + ((u >> 16) & 1);
    return (short)(u >> 16);
}
__device__ __forceinline__ short4 f4bf(float4 v) {
    short4 r; r.x = f2bf(v.x); r.y = f2bf(v.y); r.z = f2bf(v.z); r.w = f2bf(v.w); return r;
}

// ---------------------------------------------------------------------------
// 0) zero-fill helper (float4 granularity)
// ---------------------------------------------------------------------------
__global__ __launch_bounds__(256) void k_zero(float* __restrict__ p, int n4) {
    const int i = blockIdx.x * 256 + threadIdx.x;
    if (i < n4) ((float4*)p)[i] = make_float4(0.f, 0.f, 0.f, 0.f);
}

// ---------------------------------------------------------------------------
// 1) Down conv as bf16 MFMA patch GEMM, split-K x4, atomic accumulate.
//    M=4096 (b*2048+img*1024+p), K=4096 (ci*16+kh*4+kw), N=256.
//    grid (32, 2, 4), 256 thr = 4 waves, 128x128 tile, BK=32.
// ---------------------------------------------------------------------------
__global__ __launch_bounds__(256) void k_down(
    const float* __restrict__ x0, const float* __restrict__ x1,
    const float* __restrict__ w, float* __restrict__ dcn)
{
    __shared__ short sA[128 * SAP];
    __shared__ short sB[128 * SAP];
    const int tid = threadIdx.x;
    const int r0 = blockIdx.x * 128;
    const int n0 = blockIdx.y * 128;
    const int kz = blockIdx.z;
    const int b   = r0 >> 11;
    const int img = (r0 >> 10) & 1;
    const int p0  = r0 & 1023;
    const float* __restrict__ xs = img ? x1 : x0;
    const int H = img ? 256 : 128;
    const int W = img ? 64 : 128;
    const int pwsh   = img ? 4 : 5;
    const int pwmask = img ? 15 : 31;

    const int lf = tid & 7, lm = tid >> 3;
    const int ci_off = lf >> 2, kh = lf & 3;

    const int lane = tid & 63, wv = tid >> 6;
    const int wm = (wv >> 1) * 64, wn = (wv & 1) * 64;
    const int m16 = lane & 15, quad = lane >> 4;

    f32x4 acc[4][4] = {};

    for (int kt = kz * 1024; kt < kz * 1024 + 1024; kt += 32) {
        const int ci = (kt >> 4) + ci_off;
        #pragma unroll
        for (int rep = 0; rep < 4; ++rep) {
            const int m = lm + rep * 32;
            const int p = p0 + m;
            const int ph = p >> pwsh, pw = p & pwmask;
            const float4 v = *(const float4*)&xs[(size_t)((b * 256 + ci) * H + ph * 4 + kh) * W + pw * 4];
            *(short4*)&sA[m * SAP + ci_off * 16 + kh * 4] = f4bf(v);
        }
        #pragma unroll
        for (int rep = 0; rep < 4; ++rep) {
            const int n = lm + rep * 32;
            const float4 v = *(const float4*)&w[(size_t)(n0 + n) * 4096 + kt + lf * 4];
            *(short4*)&sB[n * SAP + lf * 4] = f4bf(v);
        }
        __syncthreads();
        bf16x8 af[4], bg[4];
        #pragma unroll
        for (int i = 0; i < 4; ++i) af[i] = *(bf16x8*)&sA[(wm + i * 16 + m16) * SAP + quad * 8];
        #pragma unroll
        for (int j = 0; j < 4; ++j) bg[j] = *(bf16x8*)&sB[(wn + j * 16 + m16) * SAP + quad * 8];
        #pragma unroll
        for (int i = 0; i < 4; ++i)
            #pragma unroll
            for (int j = 0; j < 4; ++j)
                acc[i][j] = __builtin_amdgcn_mfma_f32_16x16x32_bf16(af[i], bg[j], acc[i][j], 0, 0, 0);
        __syncthreads();
    }
    #pragma unroll
    for (int i = 0; i < 4; ++i) {
        const int rr = r0 + wm + i * 16 + quad * 4;
        #pragma unroll
        for (int j = 0; j < 4; ++j) {
            const int cc = n0 + wn + j * 16 + m16;
            #pragma unroll
            for (int rg = 0; rg < 4; ++rg)
                atomicAdd(&dcn[(size_t)(rr + rg) * 256 + cc], acc[i][j][rg]);
        }
    }
}

// ---------------------------------------------------------------------------
// 2) LayerNorm over C per position (+conv bias); writes xf[b, s, c] twice
// ---------------------------------------------------------------------------
__global__ __launch_bounds__(256) void k_ln(
    const float* __restrict__ dcn, const float* __restrict__ cb,
    const float* __restrict__ lw, const float* __restrict__ lb,
    float* __restrict__ xf)
{
    const int r = blockIdx.x;      // b*2048 + img*1024 + p
    const int c = threadIdx.x;
    const float v = dcn[(size_t)r * 256 + c] + cb[c];
    float s = v, s2 = v * v;
    #pragma unroll
    for (int m = 1; m < 64; m <<= 1) {
        s  += __shfl_xor(s, m);
        s2 += __shfl_xor(s2, m);
    }
    __shared__ float red[8];
    const int wid = c >> 6;
    if ((c & 63) == 0) { red[wid] = s; red[4 + wid] = s2; }
    __syncthreads();
    const float S  = red[0] + red[1] + red[2] + red[3];
    const float S2 = red[4] + red[5] + red[6] + red[7];
    const float mean = S * (1.0f / 256.0f);
    const float var  = S2 * (1.0f / 256.0f) - mean * mean;
    const float inv  = rsqrtf(var + 1e-6f);
    const float o = (v - mean) * inv * lw[c] + lb[c];
    const int b = r >> 11, ss = r & 2047;
    xf[((size_t)b * 4096 + ss) * 256 + c]        = o;
    xf[((size_t)b * 4096 + 2048 + ss) * 256 + c] = o;
}

// ---------------------------------------------------------------------------
// 3) in_proj bf16 MFMA: M=16384, K=256, N=1024; dir1 reads xf reversed.
//    grid (128, 8), 128x128 tile.
// ---------------------------------------------------------------------------
__global__ __launch_bounds__(256) void k_inproj(
    const float* __restrict__ xf, const float* __restrict__ inw,
    float* __restrict__ xz)
{
    __shared__ short sA[128 * SAP];
    __shared__ short sB[128 * SAP];
    const int tid = threadIdx.x;
    const int r0 = blockIdx.x * 128;
    const int n0 = blockIdx.y * 128;
    const int dir = r0 >> 13;
    const int b   = (r0 >> 12) & 1;
    const int s0  = r0 & 4095;

    const int lf = tid & 7, lm = tid >> 3;
    const int kl = lf * 4;
    const int lane = tid & 63, wv = tid >> 6;
    const int wm = (wv >> 1) * 64, wn = (wv & 1) * 64;
    const int m16 = lane & 15, quad = lane >> 4;

    f32x4 acc[4][4] = {};

    for (int kt = 0; kt < 256; kt += 32) {
        #pragma unroll
        for (int rep = 0; rep < 4; ++rep) {
            const int m = lm + rep * 32;
            const int se = dir ? (4095 - (s0 + m)) : (s0 + m);
            const float4 v = *(const float4*)&xf[(size_t)(b * 4096 + se) * 256 + kt + kl];
            *(short4*)&sA[m * SAP + kl] = f4bf(v);
        }
        #pragma unroll
        for (int rep = 0; rep < 4; ++rep) {
            const int n = lm + rep * 32;
            const float4 v = *(const float4*)&inw[(size_t)dir * 262144 + (size_t)(n0 + n) * 256 + kt + kl];
            *(short4*)&sB[n * SAP + kl] = f4bf(v);
        }
        __syncthreads();
        bf16x8 af[4], bg[4];
        #pragma unroll
        for (int i = 0; i < 4; ++i) af[i] = *(bf16x8*)&sA[(wm + i * 16 + m16) * SAP + quad * 8];
        #pragma unroll
        for (int j = 0; j < 4; ++j) bg[j] = *(bf16x8*)&sB[(wn + j * 16 + m16) * SAP + quad * 8];
        #pragma unroll
        for (int i = 0; i < 4; ++i)
            #pragma unroll
            for (int j = 0; j < 4; ++j)
                acc[i][j] = __builtin_amdgcn_mfma_f32_16x16x32_bf16(af[i], bg[j], acc[i][j], 0, 0, 0);
        __syncthreads();
    }
    #pragma unroll
    for (int i = 0; i < 4; ++i) {
        const int rr = r0 + wm + i * 16 + quad * 4;
        #pragma unroll
        for (int j = 0; j < 4; ++j) {
            const int cc = n0 + wn + j * 16 + m16;
            #pragma unroll
            for (int rg = 0; rg < 4; ++rg)
                xz[(size_t)(rr + rg) * 1024 + cc] = acc[i][j][rg];
        }
    }
}

// ---------------------------------------------------------------------------
// 4) causal depthwise conv (K=4) + SiLU, strip-mined (16 s/block, shift regs)
// ---------------------------------------------------------------------------
__global__ __launch_bounds__(256) void k_dwconv(
    const float* __restrict__ xz, const float* __restrict__ cw,
    const float* __restrict__ cb, float* __restrict__ xc)
{
    const int blk = blockIdx.x;       // db*256 + sc
    const int sc = blk & 255;
    const int db = blk >> 8;
    const int dir = db >> 1;
    const int s0 = sc * 16;
    #pragma unroll
    for (int dd = 0; dd < 2; ++dd) {
        const int d = threadIdx.x + dd * 256;
        const float4 wv = *(const float4*)&cw[(size_t)(dir * 512 + d) * 4];
        const float cbv = cb[dir * 512 + d];
        const float* __restrict__ px = xz + ((size_t)db * 4096 + s0) * 1024 + d;
        float* __restrict__ po = xc + ((size_t)db * 4096 + s0) * 512 + d;
        float h0 = (s0 >= 3) ? px[-3 * 1024] : 0.0f;
        float h1 = (s0 >= 2) ? px[-2 * 1024] : 0.0f;
        float h2 = (s0 >= 1) ? px[-1 * 1024] : 0.0f;
        #pragma unroll
        for (int i = 0; i < 16; ++i) {
            const float x3 = px[i * 1024];
            float a = cbv;
            a = fmaf(h0, wv.x, a); a = fmaf(h1, wv.y, a);
            a = fmaf(h2, wv.z, a); a = fmaf(x3, wv.w, a);
            po[i * 512] = silu_f(a);
            h0 = h1; h1 = h2; h2 = x3;
        }
    }
}

// ---------------------------------------------------------------------------
// 5) x_proj (fp32 tile GEMM): xdb[row, j] = sum_d xc[row,d]*xp_w[dir][j][d]
// ---------------------------------------------------------------------------
__global__ __launch_bounds__(256) void k_xdb(
    const float* __restrict__ xc, const float* __restrict__ xpw,
    float* __restrict__ xdb)
{
    __shared__ float sA[32 * LDP];
    __shared__ float sB[32 * LDP];
    const int tid = threadIdx.x;
    const int r0 = blockIdx.x * 64;
    const int dir = r0 >> 13;
    const int tm = tid >> 4, tn = tid & 15;
    const int lm = tid >> 2, lf = tid & 3;
    float acc[4][4] = {};

    const float* __restrict__ arow = &xc[(size_t)(r0 + lm) * 512];
    const int j = lm;
    const float* __restrict__ brow = &xpw[(size_t)dir * 24576 + (size_t)j * 512];

    for (int kt = 0; kt < 512; kt += 32) {
        const float4 a1 = *(const float4*)&arow[kt + lf * 4];
        const float4 a2 = *(const float4*)&arow[kt + 16 + lf * 4];
        int kb = lf * 4;
        sA[(kb + 0) * LDP + lm] = a1.x; sA[(kb + 1) * LDP + lm] = a1.y;
        sA[(kb + 2) * LDP + lm] = a1.z; sA[(kb + 3) * LDP + lm] = a1.w;
        kb = 16 + lf * 4;
        sA[(kb + 0) * LDP + lm] = a2.x; sA[(kb + 1) * LDP + lm] = a2.y;
        sA[(kb + 2) * LDP + lm] = a2.z; sA[(kb + 3) * LDP + lm] = a2.w;

        float4 b1 = make_float4(0.f, 0.f, 0.f, 0.f), b2 = b1;
        if (j < 48) {
            b1 = *(const float4*)&brow[kt + lf * 4];
            b2 = *(const float4*)&brow[kt + 16 + lf * 4];
        }
        kb = lf * 4;
        sB[(kb + 0) * LDP + lm] = b1.x; sB[(kb + 1) * LDP + lm] = b1.y;
        sB[(kb + 2) * LDP + lm] = b1.z; sB[(kb + 3) * LDP + lm] = b1.w;
        kb = 16 + lf * 4;
        sB[(kb + 0) * LDP + lm] = b2.x; sB[(kb + 1) * LDP + lm] = b2.y;
        sB[(kb + 2) * LDP + lm] = b2.z; sB[(kb + 3) * LDP + lm] = b2.w;
        __syncthreads();
        #pragma unroll
        for (int k = 0; k < 32; ++k) {
            const float4 av = *(const float4*)&sA[k * LDP + tm * 4];
            const float4 bv = *(const float4*)&sB[k * LDP + tn * 4];
            const float a_[4] = {av.x, av.y, av.z, av.w};
            const float b_[4] = {bv.x, bv.y, bv.z, bv.w};
            #pragma unroll
            for (int i = 0; i < 4; ++i)
                #pragma unroll
                for (int jj = 0; jj < 4; ++jj)
                    acc[i][jj] = fmaf(a_[i], b_[jj], acc[i][jj]);
        }
        __syncthreads();
    }
    #pragma unroll
    for (int i = 0; i < 4; ++i) {
        const size_t r = r0 + tm * 4 + i;
        #pragma unroll
        for (int jj = 0; jj < 4; ++jj) {
            const int col = tn * 4 + jj;
            if (col < 48) xdb[r * 48 + col] = acc[i][jj];
        }
    }
}

// ---------------------------------------------------------------------------
// 6) dt = softplus(xdb[:, :16] @ dt_w.T + dt_b) -> xz xin half (dead)
// ---------------------------------------------------------------------------
__global__ __launch_bounds__(256) void k_dt(
    const float* __restrict__ xdb, const float* __restrict__ dtw,
    const float* __restrict__ dtb, float* __restrict__ xz)
{
    const int row = blockIdx.x;
    const int dir = row >> 13;
    __shared__ float sx[16];
    if (threadIdx.x < 16) sx[threadIdx.x] = xdb[(size_t)row * 48 + threadIdx.x];
    __syncthreads();
    #pragma unroll
    for (int dd = 0; dd < 2; ++dd) {
        const int d = threadIdx.x + dd * 256;
        const float* wp = &dtw[(size_t)(dir * 512 + d) * 16];
        float a = dtb[dir * 512 + d];
        #pragma unroll
        for (int rr = 0; rr < 16; ++rr) a = fmaf(sx[rr], wp[rr], a);
        const float sp = (a > 15.0f) ? a : log1pf(__expf(a));
        xz[(size_t)row * 1024 + d] = sp;
    }
}

// ---------------------------------------------------------------------------
// 7a) scan pass A: per-chunk summaries (16 n-states/thread, thread = d)
// ---------------------------------------------------------------------------
__global__ __launch_bounds__(256) void k_scan_a(
    const float* __restrict__ xz, const float* __restrict__ xc,
    const float* __restrict__ xdb, const float* __restrict__ alog,
    float* __restrict__ hsum, float* __restrict__ aprod)
{
    __shared__ float sB[SCAN_L * 16];
    const int blk  = blockIdx.x;
    const int half = blk & 1;
    const int c    = (blk >> 1) & 31;
    const int db   = blk >> 6;
    const int dir  = db >> 1;
    const int d    = half * 256 + threadIdx.x;
    const int s0   = c * SCAN_L;

    for (int i = threadIdx.x; i < SCAN_L * 16; i += 256) {
        const int sl = i >> 4, j = i & 15;
        sB[i] = xdb[((size_t)db * 4096 + s0 + sl) * 48 + 16 + j];
    }
    float Av[16];
    #pragma unroll
    for (int n = 0; n < 16; ++n)
        Av[n] = -__expf(alog[(size_t)(dir * 512 + d) * 16 + n]) * 1.44269504f;
    __syncthreads();

    float h[16] = {};
    float P[16];
    #pragma unroll
    for (int n = 0; n < 16; ++n) P[n] = 1.0f;

    const float* __restrict__ pdt = xz + ((size_t)db * 4096 + s0) * 1024 + d;
    const float* __restrict__ pu  = xc + ((size_t)db * 4096 + s0) * 512 + d;
    float dtn = pdt[0], un = pu[0];
    for (int s = 0; s < SCAN_L; ++s) {
        const float dtc = dtn, uc = un;
        if (s + 1 < SCAN_L) {
            dtn = pdt[(size_t)(s + 1) * 1024];
            un  = pu[(size_t)(s + 1) * 512];
        }
        const float dtu = dtc * uc;
        const float4 b0 = *(const float4*)&sB[s * 16 + 0];
        const float4 b1 = *(const float4*)&sB[s * 16 + 4];
        const float4 b2 = *(const float4*)&sB[s * 16 + 8];
        const float4 b3 = *(const float4*)&sB[s * 16 + 12];
        const float bb[16] = {b0.x,b0.y,b0.z,b0.w, b1.x,b1.y,b1.z,b1.w,
                              b2.x,b2.y,b2.z,b2.w, b3.x,b3.y,b3.z,b3.w};
        #pragma unroll
        for (int n = 0; n < 16; ++n) {
            const float dA = exp2f(dtc * Av[n]);
            h[n] = fmaf(dA, h[n], dtu * bb[n]);
            P[n] *= dA;
        }
    }
    float* hs = hsum  + (size_t)c * 32768 + (size_t)db * 8192 + (size_t)d * 16;
    float* ap = aprod + (size_t)c * 32768 + (size_t)db * 8192 + (size_t)d * 16;
    #pragma unroll
    for (int n = 0; n < 16; n += 4) {
        *(float4*)&hs[n] = make_float4(h[n], h[n+1], h[n+2], h[n+3]);
        *(float4*)&ap[n] = make_float4(P[n], P[n+1], P[n+2], P[n+3]);
    }
}

// ---------------------------------------------------------------------------
// 7b) scan pass B: combine chunk summaries; hsum becomes h_init per chunk
// ---------------------------------------------------------------------------
__global__ __launch_bounds__(256) void k_scan_b(
    float* __restrict__ hsum, const float* __restrict__ aprod)
{
    const int t = blockIdx.x * 256 + threadIdx.x;   // 0..32767
    float h = 0.0f;
    for (int c = 0; c < SCAN_NC; ++c) {
        const float tmp = hsum[(size_t)c * 32768 + t];
        const float p   = aprod[(size_t)c * 32768 + t];
        hsum[(size_t)c * 32768 + t] = h;
        h = fmaf(p, h, tmp);
    }
}

// ---------------------------------------------------------------------------
// 7c) scan pass C: full scan from h_init, y overwrites u in place
// ---------------------------------------------------------------------------
__global__ __launch_bounds__(256) void k_scan_c(
    const float* __restrict__ xz, float* __restrict__ xc,
    const float* __restrict__ xdb, const float* __restrict__ alog,
    const float* __restrict__ dp, const float* __restrict__ hinit)
{
    __shared__ float sBC[SCAN_L * 32];
    const int blk  = blockIdx.x;
    const int half = blk & 1;
    const int c    = (blk >> 1) & 31;
    const int db   = blk >> 6;
    const int dir  = db >> 1;
    const int d    = half * 256 + threadIdx.x;
    const int s0   = c * SCAN_L;

    for (int i = threadIdx.x; i < SCAN_L * 32; i += 256) {
        const int sl = i >> 5, j = i & 31;
        sBC[i] = xdb[((size_t)db * 4096 + s0 + sl) * 48 + 16 + j];
    }
    float Av[16];
    #pragma unroll
    for (int n = 0; n < 16; ++n)
        Av[n] = -__expf(alog[(size_t)(dir * 512 + d) * 16 + n]) * 1.44269504f;
    const float Dv = dp[dir * 512 + d];

    float h[16];
    const float* hi = hinit + (size_t)c * 32768 + (size_t)db * 8192 + (size_t)d * 16;
    #pragma unroll
    for (int n = 0; n < 16; n += 4) {
        const float4 v = *(const float4*)&hi[n];
        h[n] = v.x; h[n+1] = v.y; h[n+2] = v.z; h[n+3] = v.w;
    }
    __syncthreads();

    const float* __restrict__ pdt = xz + ((size_t)db * 4096 + s0) * 1024 + d;
    float*                    pu  = xc + ((size_t)db * 4096 + s0) * 512 + d;
    float dtn = pdt[0], un = pu[0];
    for (int s = 0; s < SCAN_L; ++s) {
        const float dtc = dtn, uc = un;
        if (s + 1 < SCAN_L) {
            dtn = pdt[(size_t)(s + 1) * 1024];
            un  = pu[(size_t)(s + 1) * 512];
        }
        const float dtu = dtc * uc;
        const float4 b0 = *(const float4*)&sBC[s * 32 + 0];
        const float4 b1 = *(const float4*)&sBC[s * 32 + 4];
        const float4 b2 = *(const float4*)&sBC[s * 32 + 8];
        const float4 b3 = *(const float4*)&sBC[s * 32 + 12];
        const float4 c0 = *(const float4*)&sBC[s * 32 + 16];
        const float4 c1 = *(const float4*)&sBC[s * 32 + 20];
        const float4 c2 = *(const float4*)&sBC[s * 32 + 24];
        const float4 c3 = *(const float4*)&sBC[s * 32 + 28];
        const float bb[16] = {b0.x,b0.y,b0.z,b0.w, b1.x,b1.y,b1.z,b1.w,
                              b2.x,b2.y,b2.z,b2.w, b3.x,b3.y,b3.z,b3.w};
        const float cc[16] = {c0.x,c0.y,c0.z,c0.w, c1.x,c1.y,c1.z,c1.w,
                              c2.x,c2.y,c2.z,c2.w, c3.x,c3.y,c3.z,c3.w};
        float y0 = 0.f, y1 = 0.f, y2 = 0.f, y3 = 0.f;
        #pragma unroll
        for (int n = 0; n < 16; n += 4) {
            const float dA0 = exp2f(dtc * Av[n+0]);
            const float dA1 = exp2f(dtc * Av[n+1]);
            const float dA2 = exp2f(dtc * Av[n+2]);
            const float dA3 = exp2f(dtc * Av[n+3]);
            h[n+0] = fmaf(dA0, h[n+0], dtu * bb[n+0]);
            h[n+1] = fmaf(dA1, h[n+1], dtu * bb[n+1]);
            h[n+2] = fmaf(dA2, h[n+2], dtu * bb[n+2]);
            h[n+3] = fmaf(dA3, h[n+3], dtu * bb[n+3]);
            y0 = fmaf(h[n+0], cc[n+0], y0);
            y1 = fmaf(h[n+1], cc[n+1], y1);
            y2 = fmaf(h[n+2], cc[n+2], y2);
            y3 = fmaf(h[n+3], cc[n+3], y3);
        }
        pu[(size_t)s * 512] = fmaf(uc, Dv, (y0 + y1) + (y2 + y3));
    }
}

// ---------------------------------------------------------------------------
// 8) out_proj bf16 MFMA, split-K over dir, atomic accumulate into ym.
//    M=8192 (b*4096+s), K=512/dir, N=256. grid (64, 2, 2).
// ---------------------------------------------------------------------------
__global__ __launch_bounds__(256) void k_outproj(
    const float* __restrict__ xc,   // y
    const float* __restrict__ xz,   // z at [row*1024 + 512 + d]
    const float* __restrict__ ow,
    float* __restrict__ ym)
{
    __shared__ short sA[128 * SAP];
    __shared__ short sB[128 * SAP];
    const int tid = threadIdx.x;
    const int r0 = blockIdx.x * 128;
    const int n0 = blockIdx.y * 128;
    const int dir = blockIdx.z;
    const int bb = r0 >> 12;
    const int s0 = r0 & 4095;

    const int lf = tid & 7, lm = tid >> 3;
    const int kl = lf * 4;
    const int lane = tid & 63, wv = tid >> 6;
    const int wm = (wv >> 1) * 64, wn = (wv & 1) * 64;
    const int m16 = lane & 15, quad = lane >> 4;

    f32x4 acc[4][4] = {};

    for (int kt = 0; kt < 512; kt += 32) {
        #pragma unroll
        for (int rep = 0; rep < 4; ++rep) {
            const int m = lm + rep * 32;
            const int s = s0 + m;
            const int se = dir ? (4095 - s) : s;
            const size_t rowd = (size_t)(dir * 2 + bb) * 4096 + se;
            const float4 y4 = *(const float4*)&xc[rowd * 512 + kt + kl];
            const float4 z4 = *(const float4*)&xz[rowd * 1024 + 512 + kt + kl];
            const float4 a4 = make_float4(y4.x * silu_f(z4.x), y4.y * silu_f(z4.y),
                                          y4.z * silu_f(z4.z), y4.w * silu_f(z4.w));
            *(short4*)&sA[m * SAP + kl] = f4bf(a4);
        }
        #pragma unroll
        for (int rep = 0; rep < 4; ++rep) {
            const int n = lm + rep * 32;
            const float4 v = *(const float4*)&ow[(size_t)dir * 131072 + (size_t)(n0 + n) * 512 + kt + kl];
            *(short4*)&sB[n * SAP + kl] = f4bf(v);
        }
        __syncthreads();
        bf16x8 af[4], bg[4];
        #pragma unroll
        for (int i = 0; i < 4; ++i) af[i] = *(bf16x8*)&sA[(wm + i * 16 + m16) * SAP + quad * 8];
        #pragma unroll
        for (int j = 0; j < 4; ++j) bg[j] = *(bf16x8*)&sB[(wn + j * 16 + m16) * SAP + quad * 8];
        #pragma unroll
        for (int i = 0; i < 4; ++i)
            #pragma unroll
            for (int j = 0; j < 4; ++j)
                acc[i][j] = __builtin_amdgcn_mfma_f32_16x16x32_bf16(af[i], bg[j], acc[i][j], 0, 0, 0);
        __syncthreads();
    }
    #pragma unroll
    for (int i = 0; i < 4; ++i) {
        const int rr = r0 + wm + i * 16 + quad * 4;
        #pragma unroll
        for (int j = 0; j < 4; ++j) {
            const int cc = n0 + wn + j * 16 + m16;
            #pragma unroll
            for (int rg = 0; rg < 4; ++rg)
                atomicAdd(&ym[(size_t)(rr + rg) * 256 + cc], acc[i][j][rg]);
        }
    }
}

// ---------------------------------------------------------------------------
// 9) assemble 2D maps (0.5 merge factor applied here)
// ---------------------------------------------------------------------------
__global__ __launch_bounds__(256) void k_assemble(
    const float* __restrict__ ym, float* __restrict__ s0, float* __restrict__ s1)
{
    const int idx = blockIdx.x * 256 + threadIdx.x;   // 0..1048575
    if (idx < 524288) {
        const int j = idx & 31, i = (idx >> 5) & 31, c = (idx >> 10) & 255, b = idx >> 18;
        s0[idx] = 0.5f * (ym[((size_t)b * 4096 + i * 32 + j) * 256 + c]
                        + ym[((size_t)b * 4096 + 2048 + j * 32 + i) * 256 + c]);
    } else {
        const int k = idx - 524288;
        const int j = k & 15, i = (k >> 4) & 63, c = (k >> 10) & 255, b = k >> 18;
        s1[k] = 0.5f * (ym[((size_t)b * 4096 + 1024 + i * 16 + j) * 256 + c]
                      + ym[((size_t)b * 4096 + 3072 + j * 64 + i) * 256 + c]);
    }
}

// ---------------------------------------------------------------------------
// 10) jax bilinear x4 upsample
// ---------------------------------------------------------------------------
__device__ __forceinline__ void bil_idx(int o, int insz, int& i0, int& i1, float& f) {
    const int q = o >> 2, r = o & 3;
    f = 0.125f + 0.25f * (float)((r + 2) & 3);
    const int base = q + ((r < 2) ? -1 : 0);
    i0 = base < 0 ? 0 : base;
    i1 = (base + 1 > insz - 1) ? (insz - 1) : (base + 1);
}

__global__ __launch_bounds__(256) void k_upsample(
    const float* __restrict__ s0, const float* __restrict__ s1,
    float* __restrict__ out)
{
    const size_t idx = (size_t)blockIdx.x * 256 + threadIdx.x;
    if (idx < 8388608) {
        const int j = idx & 127, ii = (idx >> 7) & 127;
        const size_t bc = idx >> 14;
        int i0, i1, j0, j1; float fi, fj;
        bil_idx(ii, 32, i0, i1, fi);
        bil_idx(j, 32, j0, j1, fj);
        const float* S = s0 + bc * 1024;
        const float v0 = S[i0 * 32 + j0] * (1.0f - fj) + S[i0 * 32 + j1] * fj;
        const float v1 = S[i1 * 32 + j0] * (1.0f - fj) + S[i1 * 32 + j1] * fj;
        out[idx] = v0 * (1.0f - fi) + v1 * fi;
    } else {
        const size_t k = idx - 8388608;
        const int j = k & 63, ii = (k >> 6) & 255;
        const size_t bc = k >> 14;
        int i0, i1, j0, j1; float fi, fj;
        bil_idx(ii, 64, i0, i1, fi);
        bil_idx(j, 16, j0, j1, fj);
        const float* S = s1 + bc * 1024;
        const float v0 = S[i0 * 16 + j0] * (1.0f - fj) + S[i0 * 16 + j1] * fj;
        const float v1 = S[i1 * 16 + j0] * (1.0f - fj) + S[i1 * 16 + j1] * fj;
        out[idx] = v0 * (1.0f - fi) + v1 * fi;
    }
}

// ---------------------------------------------------------------------------
extern "C" void kernel_launch(void* const* d_in, const int* in_sizes, int n_in,
                              void* d_out, int out_size, void* d_ws, size_t ws_size,
                              hipStream_t stream)
{
    const float* x0   = (const float*)d_in[0];
    const float* x1   = (const float*)d_in[1];
    const float* cw   = (const float*)d_in[2];
    const float* cb   = (const float*)d_in[3];
    const float* lw   = (const float*)d_in[4];
    const float* lb   = (const float*)d_in[5];
    const float* inw  = (const float*)d_in[6];
    const float* c1w  = (const float*)d_in[7];
    const float* c1b  = (const float*)d_in[8];
    const float* xpw  = (const float*)d_in[9];
    const float* dtw  = (const float*)d_in[10];
    const float* dtb  = (const float*)d_in[11];
    const float* alog = (const float*)d_in[12];
    const float* dp   = (const float*)d_in[13];
    const float* ow   = (const float*)d_in[14];

    float* ws  = (float*)d_ws;
    // R0 [0 .. 1,048,576): dcn -> hsum -> s0m|s1m
    float* dcn = ws;
    float* hsum = ws;
    float* s0m = ws;
    float* s1m = ws + 524288;
    // R1 [1,048,576 .. 3,145,728): xf -> aprod(first 1M) -> ym
    float* xf    = ws + 1048576;
    float* aprod = ws + 1048576;
    float* ym    = ws + 1048576;
    // R2: xz (xin | z; xin half reused for dt)
    float* xz  = ws + 3145728;       // 16,777,216 f
    // R3: xc (u, then y in place)
    float* xc  = ws + 19922944;      // 8,388,608 f
    // R4: xdb
    float* xdb = ws + 28311552;      //   786,432 f
    float* out = (float*)d_out;

    k_zero    <<<1024,          256, 0, stream>>>(dcn, 262144);
    k_down    <<<dim3(32,2,4),  256, 0, stream>>>(x0, x1, cw, dcn);
    k_ln      <<<4096,          256, 0, stream>>>(dcn, cb, lw, lb, xf);
    k_inproj  <<<dim3(128,8),   256, 0, stream>>>(xf, inw, xz);
    k_dwconv  <<<1024,          256, 0, stream>>>(xz, c1w, c1b, xc);
    k_xdb     <<<256,           256, 0, stream>>>(xc, xpw, xdb);
    k_dt      <<<16384,         256, 0, stream>>>(xdb, dtw, dtb, xz);
    k_scan_a  <<<256,           256, 0, stream>>>(xz, xc, xdb, alog, hsum, aprod);
    k_scan_b  <<<128,           256, 0, stream>>>(hsum, aprod);
    k_zero    <<<2048,          256, 0, stream>>>(ym, 524288);
    k_scan_c  <<<256,           256, 0, stream>>>(xz, xc, xdb, alog, dp, hsum);
    k_outproj <<<dim3(64,2,2),  256, 0, stream>>>(xc, xz, ow, ym);
    k_assemble<<<4096,          256, 0, stream>>>(ym, s0m, s1m);
    k_upsample<<<65536,         256, 0, stream>>>(s0m, s1m, out);
}

// Round 4
// 517.625 us; speedup vs baseline: 4.7073x; 1.0903x over previous
//
#include <hip/hip_runtime.h>
#include <math.h>

#define SAP 40   // padded LDS row stride (shorts) for bf16 32-k tiles (+8 pad)

#define SCAN_NC 64
#define SCAN_L  64

typedef __attribute__((ext_vector_type(8))) short bf16x8;
typedef __attribute__((ext_vector_type(4))) float f32x4;

__device__ __forceinline__ float silu_f(float x) {
    return x * (1.0f / (1.0f + __expf(-x)));
}
__device__ __forceinline__ short f2bf(float f) {   // RNE float->bf16 (finite inputs)
    unsigned u = __float_as_uint(f);
    u += 0x7fff + ((u >> 16) & 1);
    return (short)(u >> 16);
}
__device__ __forceinline__ short4 f4bf(float4 v) {
    short4 r; r.x = f2bf(v.x); r.y = f2bf(v.y); r.z = f2bf(v.z); r.w = f2bf(v.w); return r;
}
__device__ __forceinline__ float bf2f(unsigned short u) {
    return __uint_as_float(((unsigned)u) << 16);
}

// ---------------------------------------------------------------------------
// 0) zero-fill helper (float4 granularity)
// ---------------------------------------------------------------------------
__global__ __launch_bounds__(256) void k_zero(float* __restrict__ p, int n4) {
    const int i = blockIdx.x * 256 + threadIdx.x;
    if (i < n4) ((float4*)p)[i] = make_float4(0.f, 0.f, 0.f, 0.f);
}

// ---------------------------------------------------------------------------
// 1) Down conv as bf16 MFMA patch GEMM, split-K x4, atomic accumulate.
//    M=4096 (b*2048+img*1024+p), K=4096 (ci*16+kh*4+kw), N=256.
// ---------------------------------------------------------------------------
__global__ __launch_bounds__(256) void k_down(
    const float* __restrict__ x0, const float* __restrict__ x1,
    const float* __restrict__ w, float* __restrict__ dcn)
{
    __shared__ short sA[128 * SAP];
    __shared__ short sB[128 * SAP];
    const int tid = threadIdx.x;
    const int r0 = blockIdx.x * 128;
    const int n0 = blockIdx.y * 128;
    const int kz = blockIdx.z;
    const int b   = r0 >> 11;
    const int img = (r0 >> 10) & 1;
    const int p0  = r0 & 1023;
    const float* __restrict__ xs = img ? x1 : x0;
    const int H = img ? 256 : 128;
    const int W = img ? 64 : 128;
    const int pwsh   = img ? 4 : 5;
    const int pwmask = img ? 15 : 31;

    const int lf = tid & 7, lm = tid >> 3;
    const int ci_off = lf >> 2, kh = lf & 3;

    const int lane = tid & 63, wv = tid >> 6;
    const int wm = (wv >> 1) * 64, wn = (wv & 1) * 64;
    const int m16 = lane & 15, quad = lane >> 4;

    f32x4 acc[4][4] = {};

    for (int kt = kz * 1024; kt < kz * 1024 + 1024; kt += 32) {
        const int ci = (kt >> 4) + ci_off;
        #pragma unroll
        for (int rep = 0; rep < 4; ++rep) {
            const int m = lm + rep * 32;
            const int p = p0 + m;
            const int ph = p >> pwsh, pw = p & pwmask;
            const float4 v = *(const float4*)&xs[(size_t)((b * 256 + ci) * H + ph * 4 + kh) * W + pw * 4];
            *(short4*)&sA[m * SAP + ci_off * 16 + kh * 4] = f4bf(v);
        }
        #pragma unroll
        for (int rep = 0; rep < 4; ++rep) {
            const int n = lm + rep * 32;
            const float4 v = *(const float4*)&w[(size_t)(n0 + n) * 4096 + kt + lf * 4];
            *(short4*)&sB[n * SAP + lf * 4] = f4bf(v);
        }
        __syncthreads();
        bf16x8 af[4], bg[4];
        #pragma unroll
        for (int i = 0; i < 4; ++i) af[i] = *(bf16x8*)&sA[(wm + i * 16 + m16) * SAP + quad * 8];
        #pragma unroll
        for (int j = 0; j < 4; ++j) bg[j] = *(bf16x8*)&sB[(wn + j * 16 + m16) * SAP + quad * 8];
        #pragma unroll
        for (int i = 0; i < 4; ++i)
            #pragma unroll
            for (int j = 0; j < 4; ++j)
                acc[i][j] = __builtin_amdgcn_mfma_f32_16x16x32_bf16(af[i], bg[j], acc[i][j], 0, 0, 0);
        __syncthreads();
    }
    #pragma unroll
    for (int i = 0; i < 4; ++i) {
        const int rr = r0 + wm + i * 16 + quad * 4;
        #pragma unroll
        for (int j = 0; j < 4; ++j) {
            const int cc = n0 + wn + j * 16 + m16;
            #pragma unroll
            for (int rg = 0; rg < 4; ++rg)
                atomicAdd(&dcn[(size_t)(rr + rg) * 256 + cc], acc[i][j][rg]);
        }
    }
}

// ---------------------------------------------------------------------------
// 2) LayerNorm over C per position (+conv bias); writes xf[b, s, c] twice
// ---------------------------------------------------------------------------
__global__ __launch_bounds__(256) void k_ln(
    const float* __restrict__ dcn, const float* __restrict__ cb,
    const float* __restrict__ lw, const float* __restrict__ lb,
    float* __restrict__ xf)
{
    const int r = blockIdx.x;      // b*2048 + img*1024 + p
    const int c = threadIdx.x;
    const float v = dcn[(size_t)r * 256 + c] + cb[c];
    float s = v, s2 = v * v;
    #pragma unroll
    for (int m = 1; m < 64; m <<= 1) {
        s  += __shfl_xor(s, m);
        s2 += __shfl_xor(s2, m);
    }
    __shared__ float red[8];
    const int wid = c >> 6;
    if ((c & 63) == 0) { red[wid] = s; red[4 + wid] = s2; }
    __syncthreads();
    const float S  = red[0] + red[1] + red[2] + red[3];
    const float S2 = red[4] + red[5] + red[6] + red[7];
    const float mean = S * (1.0f / 256.0f);
    const float var  = S2 * (1.0f / 256.0f) - mean * mean;
    const float inv  = rsqrtf(var + 1e-6f);
    const float o = (v - mean) * inv * lw[c] + lb[c];
    const int b = r >> 11, ss = r & 2047;
    xf[((size_t)b * 4096 + ss) * 256 + c]        = o;
    xf[((size_t)b * 4096 + 2048 + ss) * 256 + c] = o;
}

// ---------------------------------------------------------------------------
// 3) in_proj bf16 MFMA: M=16384, K=256, N=1024; dir1 reads xf reversed.
// ---------------------------------------------------------------------------
__global__ __launch_bounds__(256) void k_inproj(
    const float* __restrict__ xf, const float* __restrict__ inw,
    float* __restrict__ xz)
{
    __shared__ short sA[128 * SAP];
    __shared__ short sB[128 * SAP];
    const int tid = threadIdx.x;
    const int r0 = blockIdx.x * 128;
    const int n0 = blockIdx.y * 128;
    const int dir = r0 >> 13;
    const int b   = (r0 >> 12) & 1;
    const int s0  = r0 & 4095;

    const int lf = tid & 7, lm = tid >> 3;
    const int kl = lf * 4;
    const int lane = tid & 63, wv = tid >> 6;
    const int wm = (wv >> 1) * 64, wn = (wv & 1) * 64;
    const int m16 = lane & 15, quad = lane >> 4;

    f32x4 acc[4][4] = {};

    for (int kt = 0; kt < 256; kt += 32) {
        #pragma unroll
        for (int rep = 0; rep < 4; ++rep) {
            const int m = lm + rep * 32;
            const int se = dir ? (4095 - (s0 + m)) : (s0 + m);
            const float4 v = *(const float4*)&xf[(size_t)(b * 4096 + se) * 256 + kt + kl];
            *(short4*)&sA[m * SAP + kl] = f4bf(v);
        }
        #pragma unroll
        for (int rep = 0; rep < 4; ++rep) {
            const int n = lm + rep * 32;
            const float4 v = *(const float4*)&inw[(size_t)dir * 262144 + (size_t)(n0 + n) * 256 + kt + kl];
            *(short4*)&sB[n * SAP + kl] = f4bf(v);
        }
        __syncthreads();
        bf16x8 af[4], bg[4];
        #pragma unroll
        for (int i = 0; i < 4; ++i) af[i] = *(bf16x8*)&sA[(wm + i * 16 + m16) * SAP + quad * 8];
        #pragma unroll
        for (int j = 0; j < 4; ++j) bg[j] = *(bf16x8*)&sB[(wn + j * 16 + m16) * SAP + quad * 8];
        #pragma unroll
        for (int i = 0; i < 4; ++i)
            #pragma unroll
            for (int j = 0; j < 4; ++j)
                acc[i][j] = __builtin_amdgcn_mfma_f32_16x16x32_bf16(af[i], bg[j], acc[i][j], 0, 0, 0);
        __syncthreads();
    }
    #pragma unroll
    for (int i = 0; i < 4; ++i) {
        const int rr = r0 + wm + i * 16 + quad * 4;
        #pragma unroll
        for (int j = 0; j < 4; ++j) {
            const int cc = n0 + wn + j * 16 + m16;
            #pragma unroll
            for (int rg = 0; rg < 4; ++rg)
                xz[(size_t)(rr + rg) * 1024 + cc] = acc[i][j][rg];
        }
    }
}

// ---------------------------------------------------------------------------
// 4) causal depthwise conv (K=4) + SiLU, strip-mined (16 s/block, shift regs)
// ---------------------------------------------------------------------------
__global__ __launch_bounds__(256) void k_dwconv(
    const float* __restrict__ xz, const float* __restrict__ cw,
    const float* __restrict__ cb, float* __restrict__ xc)
{
    const int blk = blockIdx.x;       // db*256 + sc
    const int sc = blk & 255;
    const int db = blk >> 8;
    const int dir = db >> 1;
    const int s0 = sc * 16;
    #pragma unroll
    for (int dd = 0; dd < 2; ++dd) {
        const int d = threadIdx.x + dd * 256;
        const float4 wv = *(const float4*)&cw[(size_t)(dir * 512 + d) * 4];
        const float cbv = cb[dir * 512 + d];
        const float* __restrict__ px = xz + ((size_t)db * 4096 + s0) * 1024 + d;
        float* __restrict__ po = xc + ((size_t)db * 4096 + s0) * 512 + d;
        float h0 = (s0 >= 3) ? px[-3 * 1024] : 0.0f;
        float h1 = (s0 >= 2) ? px[-2 * 1024] : 0.0f;
        float h2 = (s0 >= 1) ? px[-1 * 1024] : 0.0f;
        #pragma unroll
        for (int i = 0; i < 16; ++i) {
            const float x3 = px[i * 1024];
            float a = cbv;
            a = fmaf(h0, wv.x, a); a = fmaf(h1, wv.y, a);
            a = fmaf(h2, wv.z, a); a = fmaf(x3, wv.w, a);
            po[i * 512] = silu_f(a);
            h0 = h1; h1 = h2; h2 = x3;
        }
    }
}

// ---------------------------------------------------------------------------
// 5) x_proj bf16 MFMA: M=16384, K=512, N=48 (padded 64). 64-row tiles.
// ---------------------------------------------------------------------------
__global__ __launch_bounds__(256) void k_xdb(
    const float* __restrict__ xc, const float* __restrict__ xpw,
    float* __restrict__ xdb)
{
    __shared__ short sA[64 * SAP];
    __shared__ short sB[64 * SAP];
    const int tid = threadIdx.x;
    const int r0 = blockIdx.x * 64;
    const int dir = r0 >> 13;
    const int lf = tid & 7, lm = tid >> 3;   // lm 0..31
    const int kl = lf * 4;
    const int lane = tid & 63, wv = tid >> 6;
    const int wm = wv * 16;
    const int m16 = lane & 15, quad = lane >> 4;

    f32x4 acc[4] = {};

    for (int kt = 0; kt < 512; kt += 32) {
        #pragma unroll
        for (int rep = 0; rep < 2; ++rep) {
            const int m = lm + rep * 32;
            const float4 v = *(const float4*)&xc[(size_t)(r0 + m) * 512 + kt + kl];
            *(short4*)&sA[m * SAP + kl] = f4bf(v);
        }
        #pragma unroll
        for (int rep = 0; rep < 2; ++rep) {
            const int n = lm + rep * 32;
            float4 v = make_float4(0.f, 0.f, 0.f, 0.f);
            if (n < 48) v = *(const float4*)&xpw[(size_t)dir * 24576 + (size_t)n * 512 + kt + kl];
            *(short4*)&sB[n * SAP + kl] = f4bf(v);
        }
        __syncthreads();
        bf16x8 af = *(bf16x8*)&sA[(wm + m16) * SAP + quad * 8];
        #pragma unroll
        for (int j = 0; j < 4; ++j) {
            bf16x8 bg = *(bf16x8*)&sB[(j * 16 + m16) * SAP + quad * 8];
            acc[j] = __builtin_amdgcn_mfma_f32_16x16x32_bf16(af, bg, acc[j], 0, 0, 0);
        }
        __syncthreads();
    }
    #pragma unroll
    for (int j = 0; j < 4; ++j) {
        const int cc = j * 16 + m16;
        if (cc < 48) {
            #pragma unroll
            for (int rg = 0; rg < 4; ++rg) {
                const int rr = r0 + wm + quad * 4 + rg;
                xdb[(size_t)rr * 48 + cc] = acc[j][rg];
            }
        }
    }
}

// ---------------------------------------------------------------------------
// 6) dt = softplus(xdb[:, :16] @ dt_w.T + dt_b) -> xz xin half (dead)
// ---------------------------------------------------------------------------
__global__ __launch_bounds__(256) void k_dt(
    const float* __restrict__ xdb, const float* __restrict__ dtw,
    const float* __restrict__ dtb, float* __restrict__ xz)
{
    const int row = blockIdx.x;
    const int dir = row >> 13;
    __shared__ float sx[16];
    if (threadIdx.x < 16) sx[threadIdx.x] = xdb[(size_t)row * 48 + threadIdx.x];
    __syncthreads();
    #pragma unroll
    for (int dd = 0; dd < 2; ++dd) {
        const int d = threadIdx.x + dd * 256;
        const float* wp = &dtw[(size_t)(dir * 512 + d) * 16];
        float a = dtb[dir * 512 + d];
        #pragma unroll
        for (int rr = 0; rr < 16; ++rr) a = fmaf(sx[rr], wp[rr], a);
        const float sp = (a > 15.0f) ? a : log1pf(__expf(a));
        xz[(size_t)row * 1024 + d] = sp;
    }
}

// ---------------------------------------------------------------------------
// 7a) scan pass A: per-chunk summaries (16 n-states/thread, thread = d).
//     blk = db*128 + c*2 + half. aprod stored bf16.
// ---------------------------------------------------------------------------
__global__ __launch_bounds__(256) void k_scan_a(
    const float* __restrict__ xz, const float* __restrict__ xc,
    const float* __restrict__ xdb, const float* __restrict__ alog,
    float* __restrict__ hsum, unsigned short* __restrict__ aprod)
{
    __shared__ float sB[SCAN_L * 16];
    const int blk  = blockIdx.x;
    const int half = blk & 1;
    const int c    = (blk >> 1) & (SCAN_NC - 1);
    const int db   = blk >> 7;
    const int dir  = db >> 1;
    const int d    = half * 256 + threadIdx.x;
    const int s0   = c * SCAN_L;

    for (int i = threadIdx.x; i < SCAN_L * 16; i += 256) {
        const int sl = i >> 4, j = i & 15;
        sB[i] = xdb[((size_t)db * 4096 + s0 + sl) * 48 + 16 + j];
    }
    float Av[16];
    #pragma unroll
    for (int n = 0; n < 16; ++n)
        Av[n] = -__expf(alog[(size_t)(dir * 512 + d) * 16 + n]) * 1.44269504f;
    __syncthreads();

    float h[16] = {};
    float P[16];
    #pragma unroll
    for (int n = 0; n < 16; ++n) P[n] = 1.0f;

    const float* __restrict__ pdt = xz + ((size_t)db * 4096 + s0) * 1024 + d;
    const float* __restrict__ pu  = xc + ((size_t)db * 4096 + s0) * 512 + d;
    float dtn = pdt[0], un = pu[0];
    for (int s = 0; s < SCAN_L; ++s) {
        const float dtc = dtn, uc = un;
        if (s + 1 < SCAN_L) {
            dtn = pdt[(size_t)(s + 1) * 1024];
            un  = pu[(size_t)(s + 1) * 512];
        }
        const float dtu = dtc * uc;
        const float4 b0 = *(const float4*)&sB[s * 16 + 0];
        const float4 b1 = *(const float4*)&sB[s * 16 + 4];
        const float4 b2 = *(const float4*)&sB[s * 16 + 8];
        const float4 b3 = *(const float4*)&sB[s * 16 + 12];
        const float bb[16] = {b0.x,b0.y,b0.z,b0.w, b1.x,b1.y,b1.z,b1.w,
                              b2.x,b2.y,b2.z,b2.w, b3.x,b3.y,b3.z,b3.w};
        #pragma unroll
        for (int n = 0; n < 16; ++n) {
            const float dA = exp2f(dtc * Av[n]);
            h[n] = fmaf(dA, h[n], dtu * bb[n]);
            P[n] *= dA;
        }
    }
    float*          hs = hsum  + (size_t)c * 32768 + (size_t)db * 8192 + (size_t)d * 16;
    unsigned short* ap = aprod + (size_t)c * 32768 + (size_t)db * 8192 + (size_t)d * 16;
    #pragma unroll
    for (int n = 0; n < 16; n += 4) {
        *(float4*)&hs[n] = make_float4(h[n], h[n+1], h[n+2], h[n+3]);
        *(short4*)&ap[n] = f4bf(make_float4(P[n], P[n+1], P[n+2], P[n+3]));
    }
}

// ---------------------------------------------------------------------------
// 7b) scan pass B: combine chunk summaries; hsum becomes h_init per chunk
// ---------------------------------------------------------------------------
__global__ __launch_bounds__(256) void k_scan_b(
    float* __restrict__ hsum, const unsigned short* __restrict__ aprod)
{
    const int t = blockIdx.x * 256 + threadIdx.x;   // 0..32767
    float h = 0.0f;
    for (int c = 0; c < SCAN_NC; ++c) {
        const float tmp = hsum[(size_t)c * 32768 + t];
        const float p   = bf2f(aprod[(size_t)c * 32768 + t]);
        hsum[(size_t)c * 32768 + t] = h;
        h = fmaf(p, h, tmp);
    }
}

// ---------------------------------------------------------------------------
// 7c) scan pass C: full scan from h_init, y overwrites u in place
// ---------------------------------------------------------------------------
__global__ __launch_bounds__(256) void k_scan_c(
    const float* __restrict__ xz, float* __restrict__ xc,
    const float* __restrict__ xdb, const float* __restrict__ alog,
    const float* __restrict__ dp, const float* __restrict__ hinit)
{
    __shared__ float sBC[SCAN_L * 32];
    const int blk  = blockIdx.x;
    const int half = blk & 1;
    const int c    = (blk >> 1) & (SCAN_NC - 1);
    const int db   = blk >> 7;
    const int dir  = db >> 1;
    const int d    = half * 256 + threadIdx.x;
    const int s0   = c * SCAN_L;

    for (int i = threadIdx.x; i < SCAN_L * 32; i += 256) {
        const int sl = i >> 5, j = i & 31;
        sBC[i] = xdb[((size_t)db * 4096 + s0 + sl) * 48 + 16 + j];
    }
    float Av[16];
    #pragma unroll
    for (int n = 0; n < 16; ++n)
        Av[n] = -__expf(alog[(size_t)(dir * 512 + d) * 16 + n]) * 1.44269504f;
    const float Dv = dp[dir * 512 + d];

    float h[16];
    const float* hi = hinit + (size_t)c * 32768 + (size_t)db * 8192 + (size_t)d * 16;
    #pragma unroll
    for (int n = 0; n < 16; n += 4) {
        const float4 v = *(const float4*)&hi[n];
        h[n] = v.x; h[n+1] = v.y; h[n+2] = v.z; h[n+3] = v.w;
    }
    __syncthreads();

    const float* __restrict__ pdt = xz + ((size_t)db * 4096 + s0) * 1024 + d;
    float*                    pu  = xc + ((size_t)db * 4096 + s0) * 512 + d;
    float dtn = pdt[0], un = pu[0];
    for (int s = 0; s < SCAN_L; ++s) {
        const float dtc = dtn, uc = un;
        if (s + 1 < SCAN_L) {
            dtn = pdt[(size_t)(s + 1) * 1024];
            un  = pu[(size_t)(s + 1) * 512];
        }
        const float dtu = dtc * uc;
        const float4 b0 = *(const float4*)&sBC[s * 32 + 0];
        const float4 b1 = *(const float4*)&sBC[s * 32 + 4];
        const float4 b2 = *(const float4*)&sBC[s * 32 + 8];
        const float4 b3 = *(const float4*)&sBC[s * 32 + 12];
        const float4 c0 = *(const float4*)&sBC[s * 32 + 16];
        const float4 c1 = *(const float4*)&sBC[s * 32 + 20];
        const float4 c2 = *(const float4*)&sBC[s * 32 + 24];
        const float4 c3 = *(const float4*)&sBC[s * 32 + 28];
        const float bb[16] = {b0.x,b0.y,b0.z,b0.w, b1.x,b1.y,b1.z,b1.w,
                              b2.x,b2.y,b2.z,b2.w, b3.x,b3.y,b3.z,b3.w};
        const float cc[16] = {c0.x,c0.y,c0.z,c0.w, c1.x,c1.y,c1.z,c1.w,
                              c2.x,c2.y,c2.z,c2.w, c3.x,c3.y,c3.z,c3.w};
        float y0 = 0.f, y1 = 0.f, y2 = 0.f, y3 = 0.f;
        #pragma unroll
        for (int n = 0; n < 16; n += 4) {
            const float dA0 = exp2f(dtc * Av[n+0]);
            const float dA1 = exp2f(dtc * Av[n+1]);
            const float dA2 = exp2f(dtc * Av[n+2]);
            const float dA3 = exp2f(dtc * Av[n+3]);
            h[n+0] = fmaf(dA0, h[n+0], dtu * bb[n+0]);
            h[n+1] = fmaf(dA1, h[n+1], dtu * bb[n+1]);
            h[n+2] = fmaf(dA2, h[n+2], dtu * bb[n+2]);
            h[n+3] = fmaf(dA3, h[n+3], dtu * bb[n+3]);
            y0 = fmaf(h[n+0], cc[n+0], y0);
            y1 = fmaf(h[n+1], cc[n+1], y1);
            y2 = fmaf(h[n+2], cc[n+2], y2);
            y3 = fmaf(h[n+3], cc[n+3], y3);
        }
        pu[(size_t)s * 512] = fmaf(uc, Dv, (y0 + y1) + (y2 + y3));
    }
}

// ---------------------------------------------------------------------------
// 8) out_proj bf16 MFMA, split-K over dir, atomic accumulate into ym.
// ---------------------------------------------------------------------------
__global__ __launch_bounds__(256) void k_outproj(
    const float* __restrict__ xc,   // y
    const float* __restrict__ xz,   // z at [row*1024 + 512 + d]
    const float* __restrict__ ow,
    float* __restrict__ ym)
{
    __shared__ short sA[128 * SAP];
    __shared__ short sB[128 * SAP];
    const int tid = threadIdx.x;
    const int r0 = blockIdx.x * 128;
    const int n0 = blockIdx.y * 128;
    const int dir = blockIdx.z;
    const int bb = r0 >> 12;
    const int s0 = r0 & 4095;

    const int lf = tid & 7, lm = tid >> 3;
    const int kl = lf * 4;
    const int lane = tid & 63, wv = tid >> 6;
    const int wm = (wv >> 1) * 64, wn = (wv & 1) * 64;
    const int m16 = lane & 15, quad = lane >> 4;

    f32x4 acc[4][4] = {};

    for (int kt = 0; kt < 512; kt += 32) {
        #pragma unroll
        for (int rep = 0; rep < 4; ++rep) {
            const int m = lm + rep * 32;
            const int s = s0 + m;
            const int se = dir ? (4095 - s) : s;
            const size_t rowd = (size_t)(dir * 2 + bb) * 4096 + se;
            const float4 y4 = *(const float4*)&xc[rowd * 512 + kt + kl];
            const float4 z4 = *(const float4*)&xz[rowd * 1024 + 512 + kt + kl];
            const float4 a4 = make_float4(y4.x * silu_f(z4.x), y4.y * silu_f(z4.y),
                                          y4.z * silu_f(z4.z), y4.w * silu_f(z4.w));
            *(short4*)&sA[m * SAP + kl] = f4bf(a4);
        }
        #pragma unroll
        for (int rep = 0; rep < 4; ++rep) {
            const int n = lm + rep * 32;
            const float4 v = *(const float4*)&ow[(size_t)dir * 131072 + (size_t)(n0 + n) * 512 + kt + kl];
            *(short4*)&sB[n * SAP + kl] = f4bf(v);
        }
        __syncthreads();
        bf16x8 af[4], bg[4];
        #pragma unroll
        for (int i = 0; i < 4; ++i) af[i] = *(bf16x8*)&sA[(wm + i * 16 + m16) * SAP + quad * 8];
        #pragma unroll
        for (int j = 0; j < 4; ++j) bg[j] = *(bf16x8*)&sB[(wn + j * 16 + m16) * SAP + quad * 8];
        #pragma unroll
        for (int i = 0; i < 4; ++i)
            #pragma unroll
            for (int j = 0; j < 4; ++j)
                acc[i][j] = __builtin_amdgcn_mfma_f32_16x16x32_bf16(af[i], bg[j], acc[i][j], 0, 0, 0);
        __syncthreads();
    }
    #pragma unroll
    for (int i = 0; i < 4; ++i) {
        const int rr = r0 + wm + i * 16 + quad * 4;
        #pragma unroll
        for (int j = 0; j < 4; ++j) {
            const int cc = n0 + wn + j * 16 + m16;
            #pragma unroll
            for (int rg = 0; rg < 4; ++rg)
                atomicAdd(&ym[(size_t)(rr + rg) * 256 + cc], acc[i][j][rg]);
        }
    }
}

// ---------------------------------------------------------------------------
// 9) assemble 2D maps (0.5 merge factor applied here)
// ---------------------------------------------------------------------------
__global__ __launch_bounds__(256) void k_assemble(
    const float* __restrict__ ym, float* __restrict__ s0, float* __restrict__ s1)
{
    const int idx = blockIdx.x * 256 + threadIdx.x;   // 0..1048575
    if (idx < 524288) {
        const int j = idx & 31, i = (idx >> 5) & 31, c = (idx >> 10) & 255, b = idx >> 18;
        s0[idx] = 0.5f * (ym[((size_t)b * 4096 + i * 32 + j) * 256 + c]
                        + ym[((size_t)b * 4096 + 2048 + j * 32 + i) * 256 + c]);
    } else {
        const int k = idx - 524288;
        const int j = k & 15, i = (k >> 4) & 63, c = (k >> 10) & 255, b = k >> 18;
        s1[k] = 0.5f * (ym[((size_t)b * 4096 + 1024 + i * 16 + j) * 256 + c]
                      + ym[((size_t)b * 4096 + 3072 + j * 64 + i) * 256 + c]);
    }
}

// ---------------------------------------------------------------------------
// 10) jax bilinear x4 upsample
// ---------------------------------------------------------------------------
__device__ __forceinline__ void bil_idx(int o, int insz, int& i0, int& i1, float& f) {
    const int q = o >> 2, r = o & 3;
    f = 0.125f + 0.25f * (float)((r + 2) & 3);
    const int base = q + ((r < 2) ? -1 : 0);
    i0 = base < 0 ? 0 : base;
    i1 = (base + 1 > insz - 1) ? (insz - 1) : (base + 1);
}

__global__ __launch_bounds__(256) void k_upsample(
    const float* __restrict__ s0, const float* __restrict__ s1,
    float* __restrict__ out)
{
    const size_t idx = (size_t)blockIdx.x * 256 + threadIdx.x;
    if (idx < 8388608) {
        const int j = idx & 127, ii = (idx >> 7) & 127;
        const size_t bc = idx >> 14;
        int i0, i1, j0, j1; float fi, fj;
        bil_idx(ii, 32, i0, i1, fi);
        bil_idx(j, 32, j0, j1, fj);
        const float* S = s0 + bc * 1024;
        const float v0 = S[i0 * 32 + j0] * (1.0f - fj) + S[i0 * 32 + j1] * fj;
        const float v1 = S[i1 * 32 + j0] * (1.0f - fj) + S[i1 * 32 + j1] * fj;
        out[idx] = v0 * (1.0f - fi) + v1 * fi;
    } else {
        const size_t k = idx - 8388608;
        const int j = k & 63, ii = (k >> 6) & 255;
        const size_t bc = k >> 14;
        int i0, i1, j0, j1; float fi, fj;
        bil_idx(ii, 64, i0, i1, fi);
        bil_idx(j, 16, j0, j1, fj);
        const float* S = s1 + bc * 1024;
        const float v0 = S[i0 * 16 + j0] * (1.0f - fj) + S[i0 * 16 + j1] * fj;
        const float v1 = S[i1 * 16 + j0] * (1.0f - fj) + S[i1 * 16 + j1] * fj;
        out[idx] = v0 * (1.0f - fi) + v1 * fi;
    }
}

// ---------------------------------------------------------------------------
extern "C" void kernel_launch(void* const* d_in, const int* in_sizes, int n_in,
                              void* d_out, int out_size, void* d_ws, size_t ws_size,
                              hipStream_t stream)
{
    const float* x0   = (const float*)d_in[0];
    const float* x1   = (const float*)d_in[1];
    const float* cw   = (const float*)d_in[2];
    const float* cb   = (const float*)d_in[3];
    const float* lw   = (const float*)d_in[4];
    const float* lb   = (const float*)d_in[5];
    const float* inw  = (const float*)d_in[6];
    const float* c1w  = (const float*)d_in[7];
    const float* c1b  = (const float*)d_in[8];
    const float* xpw  = (const float*)d_in[9];
    const float* dtw  = (const float*)d_in[10];
    const float* dtb  = (const float*)d_in[11];
    const float* alog = (const float*)d_in[12];
    const float* dp   = (const float*)d_in[13];
    const float* ow   = (const float*)d_in[14];

    float* ws  = (float*)d_ws;
    // R0 [0 .. 1,048,576): dcn -> aprod(bf16, 2M ushorts = 4 MB) -> s0m|s1m
    float* dcn = ws;
    unsigned short* aprod = (unsigned short*)ws;
    float* s0m = ws;
    float* s1m = ws + 524288;
    // R1 [1,048,576 .. 3,145,728): xf -> hsum (64*32768 = 2,097,152 f) -> ym
    float* xf   = ws + 1048576;
    float* hsum = ws + 1048576;
    float* ym   = ws + 1048576;
    // R2: xz (xin | z; xin half reused for dt)
    float* xz  = ws + 3145728;       // 16,777,216 f
    // R3: xc (u, then y in place)
    float* xc  = ws + 19922944;      // 8,388,608 f
    // R4: xdb
    float* xdb = ws + 28311552;      //   786,432 f
    float* out = (float*)d_out;

    k_zero    <<<1024,          256, 0, stream>>>(dcn, 262144);
    k_down    <<<dim3(32,2,4),  256, 0, stream>>>(x0, x1, cw, dcn);
    k_ln      <<<4096,          256, 0, stream>>>(dcn, cb, lw, lb, xf);
    k_inproj  <<<dim3(128,8),   256, 0, stream>>>(xf, inw, xz);
    k_dwconv  <<<1024,          256, 0, stream>>>(xz, c1w, c1b, xc);
    k_xdb     <<<256,           256, 0, stream>>>(xc, xpw, xdb);
    k_dt      <<<16384,         256, 0, stream>>>(xdb, dtw, dtb, xz);
    k_scan_a  <<<512,           256, 0, stream>>>(xz, xc, xdb, alog, hsum, aprod);
    k_scan_b  <<<128,           256, 0, stream>>>(hsum, aprod);
    k_scan_c  <<<512,           256, 0, stream>>>(xz, xc, xdb, alog, dp, hsum);
    k_zero    <<<2048,          256, 0, stream>>>(ym, 524288);
    k_outproj <<<dim3(64,2,2),  256, 0, stream>>>(xc, xz, ow, ym);
    k_assemble<<<4096,          256, 0, stream>>>(ym, s0m, s1m);
    k_upsample<<<65536,         256, 0, stream>>>(s0m, s1m, out);
}

// Round 5
// 508.002 us; speedup vs baseline: 4.7965x; 1.0189x over previous
//
#include <hip/hip_runtime.h>
#include <math.h>

#define SAP 40   // padded LDS row stride (shorts) for bf16 32-k tiles (+8 pad)

#define SCAN_NC 64
#define SCAN_L  64

typedef __attribute__((ext_vector_type(8))) short bf16x8;
typedef __attribute__((ext_vector_type(4))) float f32x4;

__device__ __forceinline__ float silu_f(float x) {
    return x * (1.0f / (1.0f + __expf(-x)));
}
__device__ __forceinline__ short f2bf(float f) {   // RNE float->bf16 (finite inputs)
    unsigned u = __float_as_uint(f);
    u += 0x7fff + ((u >> 16) & 1);
    return (short)(u >> 16);
}
__device__ __forceinline__ short4 f4bf(float4 v) {
    short4 r; r.x = f2bf(v.x); r.y = f2bf(v.y); r.z = f2bf(v.z); r.w = f2bf(v.w); return r;
}
__device__ __forceinline__ float bf2f(unsigned short u) {
    return __uint_as_float(((unsigned)u) << 16);
}

// ---------------------------------------------------------------------------
// 0) zero-fill helper (float4 granularity)
// ---------------------------------------------------------------------------
__global__ __launch_bounds__(256) void k_zero(float* __restrict__ p, int n4) {
    const int i = blockIdx.x * 256 + threadIdx.x;
    if (i < n4) ((float4*)p)[i] = make_float4(0.f, 0.f, 0.f, 0.f);
}

// ---------------------------------------------------------------------------
// 1) Down conv as bf16 MFMA patch GEMM.
//    M=4096 (b*2048+img*1024+p), K=4096 (ci*16+kh*4+kw), N=256.
//    128x64 tile, split-K x8 -> grid (32,4,8) = 1024 blocks (4/CU).
// ---------------------------------------------------------------------------
__global__ __launch_bounds__(256) void k_down(
    const float* __restrict__ x0, const float* __restrict__ x1,
    const float* __restrict__ w, float* __restrict__ dcn)
{
    __shared__ short sA[128 * SAP];
    __shared__ short sB[64 * SAP];
    const int tid = threadIdx.x;
    const int r0 = blockIdx.x * 128;
    const int n0 = blockIdx.y * 64;
    const int kz = blockIdx.z;
    const int b   = r0 >> 11;
    const int img = (r0 >> 10) & 1;
    const int p0  = r0 & 1023;
    const float* __restrict__ xs = img ? x1 : x0;
    const int H = img ? 256 : 128;
    const int W = img ? 64 : 128;
    const int pwsh   = img ? 4 : 5;
    const int pwmask = img ? 15 : 31;

    const int lf = tid & 7, lm = tid >> 3;
    const int ci_off = lf >> 2, kh = lf & 3;

    const int lane = tid & 63, wv = tid >> 6;
    const int wm = (wv >> 1) * 64, wn = (wv & 1) * 32;
    const int m16 = lane & 15, quad = lane >> 4;

    f32x4 acc[4][2] = {};

    for (int kt = kz * 512; kt < kz * 512 + 512; kt += 32) {
        const int ci = (kt >> 4) + ci_off;
        #pragma unroll
        for (int rep = 0; rep < 4; ++rep) {
            const int m = lm + rep * 32;
            const int p = p0 + m;
            const int ph = p >> pwsh, pw = p & pwmask;
            const float4 v = *(const float4*)&xs[(size_t)((b * 256 + ci) * H + ph * 4 + kh) * W + pw * 4];
            *(short4*)&sA[m * SAP + ci_off * 16 + kh * 4] = f4bf(v);
        }
        #pragma unroll
        for (int rep = 0; rep < 2; ++rep) {
            const int n = lm + rep * 32;
            const float4 v = *(const float4*)&w[(size_t)(n0 + n) * 4096 + kt + lf * 4];
            *(short4*)&sB[n * SAP + lf * 4] = f4bf(v);
        }
        __syncthreads();
        bf16x8 af[4], bg[2];
        #pragma unroll
        for (int i = 0; i < 4; ++i) af[i] = *(bf16x8*)&sA[(wm + i * 16 + m16) * SAP + quad * 8];
        #pragma unroll
        for (int j = 0; j < 2; ++j) bg[j] = *(bf16x8*)&sB[(wn + j * 16 + m16) * SAP + quad * 8];
        #pragma unroll
        for (int i = 0; i < 4; ++i)
            #pragma unroll
            for (int j = 0; j < 2; ++j)
                acc[i][j] = __builtin_amdgcn_mfma_f32_16x16x32_bf16(af[i], bg[j], acc[i][j], 0, 0, 0);
        __syncthreads();
    }
    #pragma unroll
    for (int i = 0; i < 4; ++i) {
        const int rr = r0 + wm + i * 16 + quad * 4;
        #pragma unroll
        for (int j = 0; j < 2; ++j) {
            const int cc = n0 + wn + j * 16 + m16;
            #pragma unroll
            for (int rg = 0; rg < 4; ++rg)
                atomicAdd(&dcn[(size_t)(rr + rg) * 256 + cc], acc[i][j][rg]);
        }
    }
}

// ---------------------------------------------------------------------------
// 2) LayerNorm over C per position (+conv bias); writes xf[b, s, c] twice
// ---------------------------------------------------------------------------
__global__ __launch_bounds__(256) void k_ln(
    const float* __restrict__ dcn, const float* __restrict__ cb,
    const float* __restrict__ lw, const float* __restrict__ lb,
    float* __restrict__ xf)
{
    const int r = blockIdx.x;      // b*2048 + img*1024 + p
    const int c = threadIdx.x;
    const float v = dcn[(size_t)r * 256 + c] + cb[c];
    float s = v, s2 = v * v;
    #pragma unroll
    for (int m = 1; m < 64; m <<= 1) {
        s  += __shfl_xor(s, m);
        s2 += __shfl_xor(s2, m);
    }
    __shared__ float red[8];
    const int wid = c >> 6;
    if ((c & 63) == 0) { red[wid] = s; red[4 + wid] = s2; }
    __syncthreads();
    const float S  = red[0] + red[1] + red[2] + red[3];
    const float S2 = red[4] + red[5] + red[6] + red[7];
    const float mean = S * (1.0f / 256.0f);
    const float var  = S2 * (1.0f / 256.0f) - mean * mean;
    const float inv  = rsqrtf(var + 1e-6f);
    const float o = (v - mean) * inv * lw[c] + lb[c];
    const int b = r >> 11, ss = r & 2047;
    xf[((size_t)b * 4096 + ss) * 256 + c]        = o;
    xf[((size_t)b * 4096 + 2048 + ss) * 256 + c] = o;
}

// ---------------------------------------------------------------------------
// 3) in_proj bf16 MFMA: M=16384, K=256, N=1024; dir1 reads xf reversed.
// ---------------------------------------------------------------------------
__global__ __launch_bounds__(256) void k_inproj(
    const float* __restrict__ xf, const float* __restrict__ inw,
    float* __restrict__ xz)
{
    __shared__ short sA[128 * SAP];
    __shared__ short sB[128 * SAP];
    const int tid = threadIdx.x;
    const int r0 = blockIdx.x * 128;
    const int n0 = blockIdx.y * 128;
    const int dir = r0 >> 13;
    const int b   = (r0 >> 12) & 1;
    const int s0  = r0 & 4095;

    const int lf = tid & 7, lm = tid >> 3;
    const int kl = lf * 4;
    const int lane = tid & 63, wv = tid >> 6;
    const int wm = (wv >> 1) * 64, wn = (wv & 1) * 64;
    const int m16 = lane & 15, quad = lane >> 4;

    f32x4 acc[4][4] = {};

    for (int kt = 0; kt < 256; kt += 32) {
        #pragma unroll
        for (int rep = 0; rep < 4; ++rep) {
            const int m = lm + rep * 32;
            const int se = dir ? (4095 - (s0 + m)) : (s0 + m);
            const float4 v = *(const float4*)&xf[(size_t)(b * 4096 + se) * 256 + kt + kl];
            *(short4*)&sA[m * SAP + kl] = f4bf(v);
        }
        #pragma unroll
        for (int rep = 0; rep < 4; ++rep) {
            const int n = lm + rep * 32;
            const float4 v = *(const float4*)&inw[(size_t)dir * 262144 + (size_t)(n0 + n) * 256 + kt + kl];
            *(short4*)&sB[n * SAP + kl] = f4bf(v);
        }
        __syncthreads();
        bf16x8 af[4], bg[4];
        #pragma unroll
        for (int i = 0; i < 4; ++i) af[i] = *(bf16x8*)&sA[(wm + i * 16 + m16) * SAP + quad * 8];
        #pragma unroll
        for (int j = 0; j < 4; ++j) bg[j] = *(bf16x8*)&sB[(wn + j * 16 + m16) * SAP + quad * 8];
        #pragma unroll
        for (int i = 0; i < 4; ++i)
            #pragma unroll
            for (int j = 0; j < 4; ++j)
                acc[i][j] = __builtin_amdgcn_mfma_f32_16x16x32_bf16(af[i], bg[j], acc[i][j], 0, 0, 0);
        __syncthreads();
    }
    #pragma unroll
    for (int i = 0; i < 4; ++i) {
        const int rr = r0 + wm + i * 16 + quad * 4;
        #pragma unroll
        for (int j = 0; j < 4; ++j) {
            const int cc = n0 + wn + j * 16 + m16;
            #pragma unroll
            for (int rg = 0; rg < 4; ++rg)
                xz[(size_t)(rr + rg) * 1024 + cc] = acc[i][j][rg];
        }
    }
}

// ---------------------------------------------------------------------------
// 4) causal depthwise conv (K=4) + SiLU, strip-mined (16 s/block, shift regs)
// ---------------------------------------------------------------------------
__global__ __launch_bounds__(256) void k_dwconv(
    const float* __restrict__ xz, const float* __restrict__ cw,
    const float* __restrict__ cb, float* __restrict__ xc)
{
    const int blk = blockIdx.x;       // db*256 + sc
    const int sc = blk & 255;
    const int db = blk >> 8;
    const int dir = db >> 1;
    const int s0 = sc * 16;
    #pragma unroll
    for (int dd = 0; dd < 2; ++dd) {
        const int d = threadIdx.x + dd * 256;
        const float4 wv = *(const float4*)&cw[(size_t)(dir * 512 + d) * 4];
        const float cbv = cb[dir * 512 + d];
        const float* __restrict__ px = xz + ((size_t)db * 4096 + s0) * 1024 + d;
        float* __restrict__ po = xc + ((size_t)db * 4096 + s0) * 512 + d;
        float h0 = (s0 >= 3) ? px[-3 * 1024] : 0.0f;
        float h1 = (s0 >= 2) ? px[-2 * 1024] : 0.0f;
        float h2 = (s0 >= 1) ? px[-1 * 1024] : 0.0f;
        #pragma unroll
        for (int i = 0; i < 16; ++i) {
            const float x3 = px[i * 1024];
            float a = cbv;
            a = fmaf(h0, wv.x, a); a = fmaf(h1, wv.y, a);
            a = fmaf(h2, wv.z, a); a = fmaf(x3, wv.w, a);
            po[i * 512] = silu_f(a);
            h0 = h1; h1 = h2; h2 = x3;
        }
    }
}

// ---------------------------------------------------------------------------
// 5) x_proj bf16 MFMA: M=16384, K=512, N=48 (padded 64).
//    64-row tiles, split-K x2 -> grid (256,2), atomic into zeroed xdb.
// ---------------------------------------------------------------------------
__global__ __launch_bounds__(256) void k_xdb(
    const float* __restrict__ xc, const float* __restrict__ xpw,
    float* __restrict__ xdb)
{
    __shared__ short sA[64 * SAP];
    __shared__ short sB[64 * SAP];
    const int tid = threadIdx.x;
    const int r0 = blockIdx.x * 64;
    const int kz = blockIdx.y;
    const int dir = r0 >> 13;
    const int lf = tid & 7, lm = tid >> 3;   // lm 0..31
    const int kl = lf * 4;
    const int lane = tid & 63, wv = tid >> 6;
    const int wm = wv * 16;
    const int m16 = lane & 15, quad = lane >> 4;

    f32x4 acc[4] = {};

    for (int kt = kz * 256; kt < kz * 256 + 256; kt += 32) {
        #pragma unroll
        for (int rep = 0; rep < 2; ++rep) {
            const int m = lm + rep * 32;
            const float4 v = *(const float4*)&xc[(size_t)(r0 + m) * 512 + kt + kl];
            *(short4*)&sA[m * SAP + kl] = f4bf(v);
        }
        #pragma unroll
        for (int rep = 0; rep < 2; ++rep) {
            const int n = lm + rep * 32;
            float4 v = make_float4(0.f, 0.f, 0.f, 0.f);
            if (n < 48) v = *(const float4*)&xpw[(size_t)dir * 24576 + (size_t)n * 512 + kt + kl];
            *(short4*)&sB[n * SAP + kl] = f4bf(v);
        }
        __syncthreads();
        bf16x8 af = *(bf16x8*)&sA[(wm + m16) * SAP + quad * 8];
        #pragma unroll
        for (int j = 0; j < 4; ++j) {
            bf16x8 bg = *(bf16x8*)&sB[(j * 16 + m16) * SAP + quad * 8];
            acc[j] = __builtin_amdgcn_mfma_f32_16x16x32_bf16(af, bg, acc[j], 0, 0, 0);
        }
        __syncthreads();
    }
    #pragma unroll
    for (int j = 0; j < 4; ++j) {
        const int cc = j * 16 + m16;
        if (cc < 48) {
            #pragma unroll
            for (int rg = 0; rg < 4; ++rg) {
                const int rr = r0 + wm + quad * 4 + rg;
                atomicAdd(&xdb[(size_t)rr * 48 + cc], acc[j][rg]);
            }
        }
    }
}

// ---------------------------------------------------------------------------
// 6) dt = softplus(xdb[:, :16] @ dt_w.T + dt_b) -> xz xin half (dead)
// ---------------------------------------------------------------------------
__global__ __launch_bounds__(256) void k_dt(
    const float* __restrict__ xdb, const float* __restrict__ dtw,
    const float* __restrict__ dtb, float* __restrict__ xz)
{
    const int row = blockIdx.x;
    const int dir = row >> 13;
    __shared__ float sx[16];
    if (threadIdx.x < 16) sx[threadIdx.x] = xdb[(size_t)row * 48 + threadIdx.x];
    __syncthreads();
    #pragma unroll
    for (int dd = 0; dd < 2; ++dd) {
        const int d = threadIdx.x + dd * 256;
        const float* wp = &dtw[(size_t)(dir * 512 + d) * 16];
        float a = dtb[dir * 512 + d];
        #pragma unroll
        for (int rr = 0; rr < 16; ++rr) a = fmaf(sx[rr], wp[rr], a);
        const float sp = (a > 15.0f) ? a : log1pf(__expf(a));
        xz[(size_t)row * 1024 + d] = sp;
    }
}

// ---------------------------------------------------------------------------
// 7a) scan pass A: per-chunk summaries (16 n-states/thread, thread = d).
//     blk = db*128 + c*2 + half. aprod stored bf16.
// ---------------------------------------------------------------------------
__global__ __launch_bounds__(256) void k_scan_a(
    const float* __restrict__ xz, const float* __restrict__ xc,
    const float* __restrict__ xdb, const float* __restrict__ alog,
    float* __restrict__ hsum, unsigned short* __restrict__ aprod)
{
    __shared__ float sB[SCAN_L * 16];
    const int blk  = blockIdx.x;
    const int half = blk & 1;
    const int c    = (blk >> 1) & (SCAN_NC - 1);
    const int db   = blk >> 7;
    const int dir  = db >> 1;
    const int d    = half * 256 + threadIdx.x;
    const int s0   = c * SCAN_L;

    for (int i = threadIdx.x; i < SCAN_L * 16; i += 256) {
        const int sl = i >> 4, j = i & 15;
        sB[i] = xdb[((size_t)db * 4096 + s0 + sl) * 48 + 16 + j];
    }
    float Av[16];
    #pragma unroll
    for (int n = 0; n < 16; ++n)
        Av[n] = -__expf(alog[(size_t)(dir * 512 + d) * 16 + n]) * 1.44269504f;
    __syncthreads();

    float h[16] = {};
    float P[16];
    #pragma unroll
    for (int n = 0; n < 16; ++n) P[n] = 1.0f;

    const float* __restrict__ pdt = xz + ((size_t)db * 4096 + s0) * 1024 + d;
    const float* __restrict__ pu  = xc + ((size_t)db * 4096 + s0) * 512 + d;
    float dtn = pdt[0], un = pu[0];
    for (int s = 0; s < SCAN_L; ++s) {
        const float dtc = dtn, uc = un;
        if (s + 1 < SCAN_L) {
            dtn = pdt[(size_t)(s + 1) * 1024];
            un  = pu[(size_t)(s + 1) * 512];
        }
        const float dtu = dtc * uc;
        const float4 b0 = *(const float4*)&sB[s * 16 + 0];
        const float4 b1 = *(const float4*)&sB[s * 16 + 4];
        const float4 b2 = *(const float4*)&sB[s * 16 + 8];
        const float4 b3 = *(const float4*)&sB[s * 16 + 12];
        const float bb[16] = {b0.x,b0.y,b0.z,b0.w, b1.x,b1.y,b1.z,b1.w,
                              b2.x,b2.y,b2.z,b2.w, b3.x,b3.y,b3.z,b3.w};
        #pragma unroll
        for (int n = 0; n < 16; ++n) {
            const float dA = exp2f(dtc * Av[n]);
            h[n] = fmaf(dA, h[n], dtu * bb[n]);
            P[n] *= dA;
        }
    }
    float*          hs = hsum  + (size_t)c * 32768 + (size_t)db * 8192 + (size_t)d * 16;
    unsigned short* ap = aprod + (size_t)c * 32768 + (size_t)db * 8192 + (size_t)d * 16;
    #pragma unroll
    for (int n = 0; n < 16; n += 4) {
        *(float4*)&hs[n] = make_float4(h[n], h[n+1], h[n+2], h[n+3]);
        *(short4*)&ap[n] = f4bf(make_float4(P[n], P[n+1], P[n+2], P[n+3]));
    }
}

// ---------------------------------------------------------------------------
// 7b) scan pass B: combine chunk summaries; hsum becomes h_init per chunk
// ---------------------------------------------------------------------------
__global__ __launch_bounds__(256) void k_scan_b(
    float* __restrict__ hsum, const unsigned short* __restrict__ aprod)
{
    const int t = blockIdx.x * 256 + threadIdx.x;   // 0..32767
    float h = 0.0f;
    for (int c = 0; c < SCAN_NC; ++c) {
        const float tmp = hsum[(size_t)c * 32768 + t];
        const float p   = bf2f(aprod[(size_t)c * 32768 + t]);
        hsum[(size_t)c * 32768 + t] = h;
        h = fmaf(p, h, tmp);
    }
}

// ---------------------------------------------------------------------------
// 7c) scan pass C: full scan from h_init, y overwrites u in place
// ---------------------------------------------------------------------------
__global__ __launch_bounds__(256) void k_scan_c(
    const float* __restrict__ xz, float* __restrict__ xc,
    const float* __restrict__ xdb, const float* __restrict__ alog,
    const float* __restrict__ dp, const float* __restrict__ hinit)
{
    __shared__ float sBC[SCAN_L * 32];
    const int blk  = blockIdx.x;
    const int half = blk & 1;
    const int c    = (blk >> 1) & (SCAN_NC - 1);
    const int db   = blk >> 7;
    const int dir  = db >> 1;
    const int d    = half * 256 + threadIdx.x;
    const int s0   = c * SCAN_L;

    for (int i = threadIdx.x; i < SCAN_L * 32; i += 256) {
        const int sl = i >> 5, j = i & 31;
        sBC[i] = xdb[((size_t)db * 4096 + s0 + sl) * 48 + 16 + j];
    }
    float Av[16];
    #pragma unroll
    for (int n = 0; n < 16; ++n)
        Av[n] = -__expf(alog[(size_t)(dir * 512 + d) * 16 + n]) * 1.44269504f;
    const float Dv = dp[dir * 512 + d];

    float h[16];
    const float* hi = hinit + (size_t)c * 32768 + (size_t)db * 8192 + (size_t)d * 16;
    #pragma unroll
    for (int n = 0; n < 16; n += 4) {
        const float4 v = *(const float4*)&hi[n];
        h[n] = v.x; h[n+1] = v.y; h[n+2] = v.z; h[n+3] = v.w;
    }
    __syncthreads();

    const float* __restrict__ pdt = xz + ((size_t)db * 4096 + s0) * 1024 + d;
    float*                    pu  = xc + ((size_t)db * 4096 + s0) * 512 + d;
    float dtn = pdt[0], un = pu[0];
    for (int s = 0; s < SCAN_L; ++s) {
        const float dtc = dtn, uc = un;
        if (s + 1 < SCAN_L) {
            dtn = pdt[(size_t)(s + 1) * 1024];
            un  = pu[(size_t)(s + 1) * 512];
        }
        const float dtu = dtc * uc;
        const float4 b0 = *(const float4*)&sBC[s * 32 + 0];
        const float4 b1 = *(const float4*)&sBC[s * 32 + 4];
        const float4 b2 = *(const float4*)&sBC[s * 32 + 8];
        const float4 b3 = *(const float4*)&sBC[s * 32 + 12];
        const float4 c0 = *(const float4*)&sBC[s * 32 + 16];
        const float4 c1 = *(const float4*)&sBC[s * 32 + 20];
        const float4 c2 = *(const float4*)&sBC[s * 32 + 24];
        const float4 c3 = *(const float4*)&sBC[s * 32 + 28];
        const float bb[16] = {b0.x,b0.y,b0.z,b0.w, b1.x,b1.y,b1.z,b1.w,
                              b2.x,b2.y,b2.z,b2.w, b3.x,b3.y,b3.z,b3.w};
        const float cc[16] = {c0.x,c0.y,c0.z,c0.w, c1.x,c1.y,c1.z,c1.w,
                              c2.x,c2.y,c2.z,c2.w, c3.x,c3.y,c3.z,c3.w};
        float y0 = 0.f, y1 = 0.f, y2 = 0.f, y3 = 0.f;
        #pragma unroll
        for (int n = 0; n < 16; n += 4) {
            const float dA0 = exp2f(dtc * Av[n+0]);
            const float dA1 = exp2f(dtc * Av[n+1]);
            const float dA2 = exp2f(dtc * Av[n+2]);
            const float dA3 = exp2f(dtc * Av[n+3]);
            h[n+0] = fmaf(dA0, h[n+0], dtu * bb[n+0]);
            h[n+1] = fmaf(dA1, h[n+1], dtu * bb[n+1]);
            h[n+2] = fmaf(dA2, h[n+2], dtu * bb[n+2]);
            h[n+3] = fmaf(dA3, h[n+3], dtu * bb[n+3]);
            y0 = fmaf(h[n+0], cc[n+0], y0);
            y1 = fmaf(h[n+1], cc[n+1], y1);
            y2 = fmaf(h[n+2], cc[n+2], y2);
            y3 = fmaf(h[n+3], cc[n+3], y3);
        }
        pu[(size_t)s * 512] = fmaf(uc, Dv, (y0 + y1) + (y2 + y3));
    }
}

// ---------------------------------------------------------------------------
// 8) out_proj bf16 MFMA: M=8192, N=256, K=512 per dir.
//    128x64 tile, split-K x2 per dir -> grid (64,4,4) = 1024 blocks.
//    z = dir*2 + khalf. Atomic accumulate into zeroed ym.
// ---------------------------------------------------------------------------
__global__ __launch_bounds__(256) void k_outproj(
    const float* __restrict__ xc,   // y
    const float* __restrict__ xz,   // z at [row*1024 + 512 + d]
    const float* __restrict__ ow,
    float* __restrict__ ym)
{
    __shared__ short sA[128 * SAP];
    __shared__ short sB[64 * SAP];
    const int tid = threadIdx.x;
    const int r0 = blockIdx.x * 128;
    const int n0 = blockIdx.y * 64;
    const int dir = blockIdx.z >> 1;
    const int khalf = blockIdx.z & 1;
    const int bb = r0 >> 12;
    const int s0 = r0 & 4095;

    const int lf = tid & 7, lm = tid >> 3;
    const int kl = lf * 4;
    const int lane = tid & 63, wv = tid >> 6;
    const int wm = (wv >> 1) * 64, wn = (wv & 1) * 32;
    const int m16 = lane & 15, quad = lane >> 4;

    f32x4 acc[4][2] = {};

    for (int kt = khalf * 256; kt < khalf * 256 + 256; kt += 32) {
        #pragma unroll
        for (int rep = 0; rep < 4; ++rep) {
            const int m = lm + rep * 32;
            const int s = s0 + m;
            const int se = dir ? (4095 - s) : s;
            const size_t rowd = (size_t)(dir * 2 + bb) * 4096 + se;
            const float4 y4 = *(const float4*)&xc[rowd * 512 + kt + kl];
            const float4 z4 = *(const float4*)&xz[rowd * 1024 + 512 + kt + kl];
            const float4 a4 = make_float4(y4.x * silu_f(z4.x), y4.y * silu_f(z4.y),
                                          y4.z * silu_f(z4.z), y4.w * silu_f(z4.w));
            *(short4*)&sA[m * SAP + kl] = f4bf(a4);
        }
        #pragma unroll
        for (int rep = 0; rep < 2; ++rep) {
            const int n = lm + rep * 32;
            const float4 v = *(const float4*)&ow[(size_t)dir * 131072 + (size_t)(n0 + n) * 512 + kt + kl];
            *(short4*)&sB[n * SAP + kl] = f4bf(v);
        }
        __syncthreads();
        bf16x8 af[4], bg[2];
        #pragma unroll
        for (int i = 0; i < 4; ++i) af[i] = *(bf16x8*)&sA[(wm + i * 16 + m16) * SAP + quad * 8];
        #pragma unroll
        for (int j = 0; j < 2; ++j) bg[j] = *(bf16x8*)&sB[(wn + j * 16 + m16) * SAP + quad * 8];
        #pragma unroll
        for (int i = 0; i < 4; ++i)
            #pragma unroll
            for (int j = 0; j < 2; ++j)
                acc[i][j] = __builtin_amdgcn_mfma_f32_16x16x32_bf16(af[i], bg[j], acc[i][j], 0, 0, 0);
        __syncthreads();
    }
    #pragma unroll
    for (int i = 0; i < 4; ++i) {
        const int rr = r0 + wm + i * 16 + quad * 4;
        #pragma unroll
        for (int j = 0; j < 2; ++j) {
            const int cc = n0 + wn + j * 16 + m16;
            #pragma unroll
            for (int rg = 0; rg < 4; ++rg)
                atomicAdd(&ym[(size_t)(rr + rg) * 256 + cc], acc[i][j][rg]);
        }
    }
}

// ---------------------------------------------------------------------------
// 9) assemble 2D maps (0.5 merge factor applied here)
// ---------------------------------------------------------------------------
__global__ __launch_bounds__(256) void k_assemble(
    const float* __restrict__ ym, float* __restrict__ s0, float* __restrict__ s1)
{
    const int idx = blockIdx.x * 256 + threadIdx.x;   // 0..1048575
    if (idx < 524288) {
        const int j = idx & 31, i = (idx >> 5) & 31, c = (idx >> 10) & 255, b = idx >> 18;
        s0[idx] = 0.5f * (ym[((size_t)b * 4096 + i * 32 + j) * 256 + c]
                        + ym[((size_t)b * 4096 + 2048 + j * 32 + i) * 256 + c]);
    } else {
        const int k = idx - 524288;
        const int j = k & 15, i = (k >> 4) & 63, c = (k >> 10) & 255, b = k >> 18;
        s1[k] = 0.5f * (ym[((size_t)b * 4096 + 1024 + i * 16 + j) * 256 + c]
                      + ym[((size_t)b * 4096 + 3072 + j * 64 + i) * 256 + c]);
    }
}

// ---------------------------------------------------------------------------
// 10) jax bilinear x4 upsample
// ---------------------------------------------------------------------------
__device__ __forceinline__ void bil_idx(int o, int insz, int& i0, int& i1, float& f) {
    const int q = o >> 2, r = o & 3;
    f = 0.125f + 0.25f * (float)((r + 2) & 3);
    const int base = q + ((r < 2) ? -1 : 0);
    i0 = base < 0 ? 0 : base;
    i1 = (base + 1 > insz - 1) ? (insz - 1) : (base + 1);
}

__global__ __launch_bounds__(256) void k_upsample(
    const float* __restrict__ s0, const float* __restrict__ s1,
    float* __restrict__ out)
{
    const size_t idx = (size_t)blockIdx.x * 256 + threadIdx.x;
    if (idx < 8388608) {
        const int j = idx & 127, ii = (idx >> 7) & 127;
        const size_t bc = idx >> 14;
        int i0, i1, j0, j1; float fi, fj;
        bil_idx(ii, 32, i0, i1, fi);
        bil_idx(j, 32, j0, j1, fj);
        const float* S = s0 + bc * 1024;
        const float v0 = S[i0 * 32 + j0] * (1.0f - fj) + S[i0 * 32 + j1] * fj;
        const float v1 = S[i1 * 32 + j0] * (1.0f - fj) + S[i1 * 32 + j1] * fj;
        out[idx] = v0 * (1.0f - fi) + v1 * fi;
    } else {
        const size_t k = idx - 8388608;
        const int j = k & 63, ii = (k >> 6) & 255;
        const size_t bc = k >> 14;
        int i0, i1, j0, j1; float fi, fj;
        bil_idx(ii, 64, i0, i1, fi);
        bil_idx(j, 16, j0, j1, fj);
        const float* S = s1 + bc * 1024;
        const float v0 = S[i0 * 16 + j0] * (1.0f - fj) + S[i0 * 16 + j1] * fj;
        const float v1 = S[i1 * 16 + j0] * (1.0f - fj) + S[i1 * 16 + j1] * fj;
        out[idx] = v0 * (1.0f - fi) + v1 * fi;
    }
}

// ---------------------------------------------------------------------------
extern "C" void kernel_launch(void* const* d_in, const int* in_sizes, int n_in,
                              void* d_out, int out_size, void* d_ws, size_t ws_size,
                              hipStream_t stream)
{
    const float* x0   = (const float*)d_in[0];
    const float* x1   = (const float*)d_in[1];
    const float* cw   = (const float*)d_in[2];
    const float* cb   = (const float*)d_in[3];
    const float* lw   = (const float*)d_in[4];
    const float* lb   = (const float*)d_in[5];
    const float* inw  = (const float*)d_in[6];
    const float* c1w  = (const float*)d_in[7];
    const float* c1b  = (const float*)d_in[8];
    const float* xpw  = (const float*)d_in[9];
    const float* dtw  = (const float*)d_in[10];
    const float* dtb  = (const float*)d_in[11];
    const float* alog = (const float*)d_in[12];
    const float* dp   = (const float*)d_in[13];
    const float* ow   = (const float*)d_in[14];

    float* ws  = (float*)d_ws;
    // R0 [0 .. 1,048,576): dcn -> aprod(bf16, 2M ushorts = 4 MB) -> s0m|s1m
    float* dcn = ws;
    unsigned short* aprod = (unsigned short*)ws;
    float* s0m = ws;
    float* s1m = ws + 524288;
    // R1 [1,048,576 .. 3,145,728): xf -> hsum (64*32768 = 2,097,152 f) -> ym
    float* xf   = ws + 1048576;
    float* hsum = ws + 1048576;
    float* ym   = ws + 1048576;
    // R2: xz (xin | z; xin half reused for dt)
    float* xz  = ws + 3145728;       // 16,777,216 f
    // R3: xc (u, then y in place)
    float* xc  = ws + 19922944;      // 8,388,608 f
    // R4: xdb
    float* xdb = ws + 28311552;      //   786,432 f
    float* out = (float*)d_out;

    k_zero    <<<1024,          256, 0, stream>>>(dcn, 262144);
    k_down    <<<dim3(32,4,8),  256, 0, stream>>>(x0, x1, cw, dcn);
    k_ln      <<<4096,          256, 0, stream>>>(dcn, cb, lw, lb, xf);
    k_inproj  <<<dim3(128,8),   256, 0, stream>>>(xf, inw, xz);
    k_dwconv  <<<1024,          256, 0, stream>>>(xz, c1w, c1b, xc);
    k_zero    <<<768,           256, 0, stream>>>(xdb, 196608);
    k_xdb     <<<dim3(256,2),   256, 0, stream>>>(xc, xpw, xdb);
    k_dt      <<<16384,         256, 0, stream>>>(xdb, dtw, dtb, xz);
    k_scan_a  <<<512,           256, 0, stream>>>(xz, xc, xdb, alog, hsum, aprod);
    k_scan_b  <<<128,           256, 0, stream>>>(hsum, aprod);
    k_scan_c  <<<512,           256, 0, stream>>>(xz, xc, xdb, alog, dp, hsum);
    k_zero    <<<2048,          256, 0, stream>>>(ym, 524288);
    k_outproj <<<dim3(64,4,4),  256, 0, stream>>>(xc, xz, ow, ym);
    k_assemble<<<4096,          256, 0, stream>>>(ym, s0m, s1m);
    k_upsample<<<65536,         256, 0, stream>>>(s0m, s1m, out);
}